// Round 2
// baseline (569.770 us; speedup 1.0000x reference)
//
#include <hip/hip_runtime.h>
#include <hip/hip_bf16.h>

#define EPS_LN 1e-5f
#define NCAP 51200            // node-capacity for LDS histogram (n = 50000)

typedef int ivec4 __attribute__((ext_vector_type(4)));   // clang vector: OK for nontemporal builtins

// ===========================================================================
// R22 (= R21 + compile fix): fill_part rewrite — grid-stride int4 non-temporal
// reads (2048 blocks, ~6 iters/thread) replace the one-edge-per-thread
// latency-bound version. nt loads keep the streaming col/row reads from
// evicting the dirty scatter lines out of the partition-owning XCD's L2
// (WRITE_SIZE was 10x payload). count_lds: 256 blocks + ivec4 nt reads.
// nhead_f32: float4 loads + LDS-staged W. Everything else identical to R20.
// ===========================================================================

__global__ __launch_bounds__(256) void count_lds(const int* __restrict__ col,
                                                 int* __restrict__ cnt,
                                                 int E, int n, int nb) {
    __shared__ unsigned int hist[NCAP / 2];   // 2x16-bit counters/word, 100KB
    int t = threadIdx.x;
    for (int i = t; i < NCAP / 2; i += 256) hist[i] = 0;
    __syncthreads();

    int E4 = E >> 2;
    int per = (E4 + nb - 1) / nb;
    int s0 = blockIdx.x * per;
    int s1 = s0 + per; if (s1 > E4) s1 = E4;
    for (int i = s0 + t; i < s1; i += 256) {
        ivec4 c = __builtin_nontemporal_load(((const ivec4*)col) + i);
        atomicAdd(&hist[c.x >> 1], (c.x & 1) ? 65536u : 1u);
        atomicAdd(&hist[c.y >> 1], (c.y & 1) ? 65536u : 1u);
        atomicAdd(&hist[c.z >> 1], (c.z & 1) ? 65536u : 1u);
        atomicAdd(&hist[c.w >> 1], (c.w & 1) ? 65536u : 1u);
    }
    if (blockIdx.x == 0) {           // tail (E % 4) — none for E=1.6M, safety
        for (int i = (E4 << 2) + t; i < E; i += 256) {
            int c = col[i];
            atomicAdd(&hist[c >> 1], (c & 1) ? 65536u : 1u);
        }
    }
    __syncthreads();

    // coalesced flush, block-staggered start to decorrelate atomic addresses
    int half = (n + 1) >> 1;
    int start = (((size_t)blockIdx.x * half) / nb) & ~(size_t)255;
    for (int j = t; j < half; j += 256) {
        int i = start + j; if (i >= half) i -= half;
        unsigned int v = hist[i];
        if (v) {
            unsigned int lo = v & 0xffffu, hi = v >> 16;
            if (lo) atomicAdd(&cnt[2 * i], (int)lo);
            if (hi && 2 * i + 1 < n) atomicAdd(&cnt[2 * i + 1], (int)hi);
        }
    }
}

__global__ __launch_bounds__(256) void scan_p1(const int* __restrict__ cnt,
                                               int* __restrict__ partial, int n) {
    __shared__ int s[256];
    int t = threadIdx.x;
    int i = blockIdx.x * 256 + t;
    s[t] = (i < n) ? cnt[i] : 0;
    __syncthreads();
    for (int st = 128; st > 0; st >>= 1) {
        if (t < st) s[t] += s[t + st];
        __syncthreads();
    }
    if (t == 0) partial[blockIdx.x] = s[0];
}

__global__ __launch_bounds__(256) void scan_p2(int* __restrict__ partial,
                                               int* __restrict__ rowPtr,
                                               int n, int nb) {
    if (threadIdx.x == 0) {
        int run = 0;
        for (int i = 0; i < nb; i++) { int v = partial[i]; partial[i] = run; run += v; }
        rowPtr[n] = run;
    }
}

__global__ __launch_bounds__(256) void scan_p3(const int* __restrict__ cnt,
                                               const int* __restrict__ partial,
                                               int* __restrict__ rowPtr,
                                               int* __restrict__ cursor,
                                               float* __restrict__ dinv, int n) {
    __shared__ int sh[256];
    int t = threadIdx.x;
    int i = blockIdx.x * 256 + t;
    int v = (i < n) ? cnt[i] : 0;
    sh[t] = v;
    __syncthreads();
    for (int d = 1; d < 256; d <<= 1) {
        int add = (t >= d) ? sh[t - d] : 0;
        __syncthreads();
        sh[t] += add;
        __syncthreads();
    }
    if (i < n) {
        int excl = sh[t] - v + partial[blockIdx.x];
        rowPtr[i] = excl;
        cursor[i] = excl;
        dinv[i] = rsqrtf((float)v + 1.0f);   // +1 self-loop
    }
}

// R22: grid-stride, ivec4, non-temporal reads. 8 partitions, p = blockIdx&7
// stays XCD-aligned under round-robin dispatch so each partition's scatter
// range (800KB srcList + 100KB cursor) lives in one XCD's L2; nt on the
// streaming reads keeps those dirty lines resident.
__global__ __launch_bounds__(256) void fill_part(const int* __restrict__ row,
                                                 const int* __restrict__ col,
                                                 int* __restrict__ cursor,
                                                 int* __restrict__ srcList,
                                                 int E, int rw) {
    const int p = blockIdx.x & 7;
    const int nb = gridDim.x >> 3;
    const int bi = blockIdx.x >> 3;
    const int lo = p * rw;
    const int hi = lo + rw;
    const int E4 = E >> 2;
    const int stride = nb * 256;
    for (int i4 = bi * 256 + threadIdx.x; i4 < E4; i4 += stride) {
        ivec4 c4 = __builtin_nontemporal_load(((const ivec4*)col) + i4);
        ivec4 r4 = __builtin_nontemporal_load(((const ivec4*)row) + i4);
        if (c4.x >= lo && c4.x < hi) { int pos = atomicAdd(&cursor[c4.x], 1); srcList[pos] = r4.x; }
        if (c4.y >= lo && c4.y < hi) { int pos = atomicAdd(&cursor[c4.y], 1); srcList[pos] = r4.y; }
        if (c4.z >= lo && c4.z < hi) { int pos = atomicAdd(&cursor[c4.z], 1); srcList[pos] = r4.z; }
        if (c4.w >= lo && c4.w < hi) { int pos = atomicAdd(&cursor[c4.w], 1); srcList[pos] = r4.w; }
    }
    if (bi == 0) {                   // tail (E % 4) — none for E=1.6M, safety
        for (int i = (E4 << 2) + threadIdx.x; i < E; i += 256) {
            int c = col[i];
            if (c >= lo && c < hi) {
                int pos = atomicAdd(&cursor[c], 1);
                srcList[pos] = row[i];
            }
        }
    }
}

// ---------------------------------------------------------------------------
// Tiled GEMM: 128x128 block tile, 256 threads, 8x8 per thread, BK=16.
// ---------------------------------------------------------------------------
__global__ __launch_bounds__(256) void gemm_nk(const float* __restrict__ A,
                                               const float* __restrict__ W,
                                               const float* __restrict__ bias,
                                               const float* __restrict__ dinv,
                                               float* __restrict__ C,
                                               unsigned short* __restrict__ Cb,
                                               int n, int addb) {
    __shared__ float As[128][17];
    __shared__ float Ws[16][128];

    const int tx = threadIdx.x;
    const int row0 = blockIdx.x * 128;
    const int jg = (tx & 15) * 8;
    const int ig = (tx >> 4) * 8;

    float acc[8][8];
#pragma unroll
    for (int r = 0; r < 8; r++)
#pragma unroll
        for (int c = 0; c < 8; c++) acc[r][c] = 0.f;

    for (int k0 = 0; k0 < 128; k0 += 16) {
        {
#pragma unroll
            for (int q = 0; q < 2; q++) {
                int f = tx * 2 + q;
                int r = f >> 2;
                int c4 = (f & 3) * 4;
                int grow = row0 + r;
                float4 v = make_float4(0.f, 0.f, 0.f, 0.f);
                if (grow < n) v = *(const float4*)(A + (size_t)grow * 128 + k0 + c4);
                As[r][c4 + 0] = v.x; As[r][c4 + 1] = v.y;
                As[r][c4 + 2] = v.z; As[r][c4 + 3] = v.w;
            }
        }
        {
#pragma unroll
            for (int q = 0; q < 2; q++) {
                int f = tx * 2 + q;
                int kr = f >> 5;
                int c4 = (f & 31) * 4;
                *(float4*)&Ws[kr][c4] = *(const float4*)(W + (size_t)(k0 + kr) * 128 + c4);
            }
        }
        __syncthreads();
#pragma unroll
        for (int kk = 0; kk < 16; kk++) {
            float4 w0 = *(const float4*)&Ws[kk][jg];
            float4 w1 = *(const float4*)&Ws[kk][jg + 4];
            float wv[8] = {w0.x, w0.y, w0.z, w0.w, w1.x, w1.y, w1.z, w1.w};
#pragma unroll
            for (int r = 0; r < 8; r++) {
                float a = As[ig + r][kk];
#pragma unroll
                for (int c = 0; c < 8; c++) acc[r][c] += a * wv[c];
            }
        }
        __syncthreads();
    }

    float bv[8] = {0.f, 0.f, 0.f, 0.f, 0.f, 0.f, 0.f, 0.f};
    if (addb) {
        float4 b0 = *(const float4*)(bias + jg);
        float4 b1 = *(const float4*)(bias + jg + 4);
        bv[0] = b0.x; bv[1] = b0.y; bv[2] = b0.z; bv[3] = b0.w;
        bv[4] = b1.x; bv[5] = b1.y; bv[6] = b1.z; bv[7] = b1.w;
    }
#pragma unroll
    for (int r = 0; r < 8; r++) {
        int grow = row0 + ig + r;
        if (grow < n) {
            float o[8];
#pragma unroll
            for (int c = 0; c < 8; c++) o[c] = acc[r][c] + bv[c];
            *(float4*)(C + (size_t)grow * 128 + jg)     = make_float4(o[0], o[1], o[2], o[3]);
            *(float4*)(C + (size_t)grow * 128 + jg + 4) = make_float4(o[4], o[5], o[6], o[7]);
            if (Cb) {
                float dr = dinv[grow];
                ushort4 u0, u1;
                __hip_bfloat16 t;
                t = __float2bfloat16(o[0] * dr); u0.x = *(unsigned short*)&t;
                t = __float2bfloat16(o[1] * dr); u0.y = *(unsigned short*)&t;
                t = __float2bfloat16(o[2] * dr); u0.z = *(unsigned short*)&t;
                t = __float2bfloat16(o[3] * dr); u0.w = *(unsigned short*)&t;
                t = __float2bfloat16(o[4] * dr); u1.x = *(unsigned short*)&t;
                t = __float2bfloat16(o[5] * dr); u1.y = *(unsigned short*)&t;
                t = __float2bfloat16(o[6] * dr); u1.z = *(unsigned short*)&t;
                t = __float2bfloat16(o[7] * dr); u1.w = *(unsigned short*)&t;
                *(ushort4*)(Cb + (size_t)grow * 128 + jg)     = u0;
                *(ushort4*)(Cb + (size_t)grow * 128 + jg + 4) = u1;
            }
        }
    }
}

// ---------------------------------------------------------------------------
// Fused gather (bf16 pre-scaled) + self-loop(f32) + bias + relu (+ LN).
// ---------------------------------------------------------------------------
template<bool DO_LN>
__global__ __launch_bounds__(256) void agg_post(const float* __restrict__ h,
                                                const unsigned int* __restrict__ hb,
                                                const int* __restrict__ rowPtr,
                                                const int* __restrict__ srcList,
                                                const float* __restrict__ dinv,
                                                const float* __restrict__ b,
                                                const float* __restrict__ g,
                                                const float* __restrict__ beta,
                                                float* __restrict__ out, int n) {
    int wid = (blockIdx.x * 256 + threadIdx.x) >> 6;
    int lane = threadIdx.x & 63;
    if (wid >= n) return;
    int e0 = rowPtr[wid], e1 = rowPtr[wid + 1];
    float dc = dinv[wid];
    size_t base = (size_t)wid * 128 + lane * 2;
    float2 hs = *(const float2*)(h + base);
    float ax = hs.x * dc * dc;
    float ay = hs.y * dc * dc;

    int e = e0;
    for (; e + 8 <= e1; e += 8) {
        int r0 = srcList[e + 0], r1 = srcList[e + 1];
        int r2 = srcList[e + 2], r3 = srcList[e + 3];
        int r4 = srcList[e + 4], r5 = srcList[e + 5];
        int r6 = srcList[e + 6], r7 = srcList[e + 7];
        unsigned int u0 = hb[(size_t)r0 * 64 + lane];
        unsigned int u1 = hb[(size_t)r1 * 64 + lane];
        unsigned int u2 = hb[(size_t)r2 * 64 + lane];
        unsigned int u3 = hb[(size_t)r3 * 64 + lane];
        unsigned int u4 = hb[(size_t)r4 * 64 + lane];
        unsigned int u5 = hb[(size_t)r5 * 64 + lane];
        unsigned int u6 = hb[(size_t)r6 * 64 + lane];
        unsigned int u7 = hb[(size_t)r7 * 64 + lane];
        ax += __uint_as_float(u0 << 16) * dc;  ay += __uint_as_float(u0 & 0xffff0000u) * dc;
        ax += __uint_as_float(u1 << 16) * dc;  ay += __uint_as_float(u1 & 0xffff0000u) * dc;
        ax += __uint_as_float(u2 << 16) * dc;  ay += __uint_as_float(u2 & 0xffff0000u) * dc;
        ax += __uint_as_float(u3 << 16) * dc;  ay += __uint_as_float(u3 & 0xffff0000u) * dc;
        ax += __uint_as_float(u4 << 16) * dc;  ay += __uint_as_float(u4 & 0xffff0000u) * dc;
        ax += __uint_as_float(u5 << 16) * dc;  ay += __uint_as_float(u5 & 0xffff0000u) * dc;
        ax += __uint_as_float(u6 << 16) * dc;  ay += __uint_as_float(u6 & 0xffff0000u) * dc;
        ax += __uint_as_float(u7 << 16) * dc;  ay += __uint_as_float(u7 & 0xffff0000u) * dc;
    }
    for (; e < e1; e++) {
        int r = srcList[e];
        unsigned int u = hb[(size_t)r * 64 + lane];
        ax += __uint_as_float(u << 16) * dc;
        ay += __uint_as_float(u & 0xffff0000u) * dc;
    }

    ax = fmaxf(ax + b[lane * 2 + 0], 0.f);
    ay = fmaxf(ay + b[lane * 2 + 1], 0.f);
    if (DO_LN) {
        float s = ax + ay;
#pragma unroll
        for (int m = 32; m >= 1; m >>= 1) s += __shfl_xor(s, m, 64);
        float mu = s * (1.f / 128.f);
        float dx = ax - mu, dy = ay - mu;
        float sq = dx * dx + dy * dy;
#pragma unroll
        for (int m = 32; m >= 1; m >>= 1) sq += __shfl_xor(sq, m, 64);
        float rs = rsqrtf(sq * (1.f / 128.f) + EPS_LN);
        ax = dx * rs * g[lane * 2 + 0] + beta[lane * 2 + 0];
        ay = dy * rs * g[lane * 2 + 1] + beta[lane * 2 + 1];
    }
    *(float2*)(out + base) = make_float2(ax, ay);
}

// ---------------------------------------------------------------------------
__global__ __launch_bounds__(256) void nhead_f32(const float* __restrict__ hp,
                                                 const float* __restrict__ W,
                                                 const float* __restrict__ b,
                                                 float* __restrict__ out, int n) {
    __shared__ float Ws[384];
    int t = threadIdx.x;
    if (t < 192) { Ws[t] = W[t]; Ws[t + 192] = W[t + 192]; }
    __syncthreads();
    int i = blockIdx.x * 256 + t;
    if (i >= n) return;
    float p0 = b[0], p1 = b[1], p2 = b[2];
    const float4* h4 = (const float4*)(hp + (size_t)i * 128);
#pragma unroll
    for (int k4 = 0; k4 < 32; k4++) {
        float4 v = h4[k4];
        const float* w = &Ws[k4 * 12];
        p0 += v.x * w[0] + v.y * w[3] + v.z * w[6] + v.w * w[9];
        p1 += v.x * w[1] + v.y * w[4] + v.z * w[7] + v.w * w[10];
        p2 += v.x * w[2] + v.y * w[5] + v.z * w[8] + v.w * w[11];
    }
    out[(size_t)i * 3 + 0] = p0;
    out[(size_t)i * 3 + 1] = p1;
    out[(size_t)i * 3 + 2] = p2;
}

// ---------------------------------------------------------------------------
extern "C" void kernel_launch(void* const* d_in, const int* in_sizes, int n_in,
                              void* d_out, int out_size, void* d_ws, size_t ws_size,
                              hipStream_t stream) {
    const float* x   = (const float*)d_in[0];
    const int* ei    = (const int*)d_in[1];
    const float* W1  = (const float*)d_in[2];
    const float* b1  = (const float*)d_in[3];
    const float* W2  = (const float*)d_in[4];
    const float* b2  = (const float*)d_in[5];
    const float* W3  = (const float*)d_in[6];
    const float* b3  = (const float*)d_in[7];
    const float* g1  = (const float*)d_in[8];
    const float* be1 = (const float*)d_in[9];
    const float* g2  = (const float*)d_in[10];
    const float* be2 = (const float*)d_in[11];
    const float* Wp1 = (const float*)d_in[12];
    const float* bp1 = (const float*)d_in[13];
    const float* Wp2 = (const float*)d_in[14];
    const float* bp2 = (const float*)d_in[15];
    float* out = (float*)d_out;

    const int n = in_sizes[0] / 128;   // 50000
    const int E = in_sizes[1] / 2;     // 1600000
    const int* row = ei;
    const int* col = ei + E;

    char* ws = (char*)d_ws;
    size_t nA  = ((size_t)n * 4 + 255) & ~(size_t)255;
    size_t nA1 = ((size_t)(n + 1) * 4 + 255) & ~(size_t)255;
    size_t eA  = ((size_t)E * 4 + 255) & ~(size_t)255;
    size_t hbA = ((size_t)n * 128 * 2 + 255) & ~(size_t)255;
    int*   cnt     = (int*)ws;
    int*   rowPtr  = (int*)(ws + nA);
    int*   cursor  = (int*)(ws + nA + nA1);
    float* dinvp   = (float*)(ws + 2 * nA + nA1);
    int*   partial = (int*)(ws + 3 * nA + nA1);
    int*   srcList = (int*)(ws + 4 * nA + nA1);
    unsigned short* hb = (unsigned short*)(ws + 4 * nA + nA1 + eA);
    float* bufA    = (float*)(ws + 4 * nA + nA1 + eA + hbA);
    float* bufB    = bufA + (size_t)n * 128;

    const int gemmBlocks = (n + 127) / 128;
    const int nodeWaveBlocks = (n + 3) / 4;
    const int nodeBlocks = (n + 255) / 256;

    const int P = 8;
    const int rw = (n + P - 1) / P;
    const int countBlocks = 256;       // LDS-histogram blocks
    const int fillBlocks = 8 * 256;    // 8 partitions x 256 grid-stride blocks

    // CSR build
    hipMemsetAsync(cnt, 0, (size_t)n * 4, stream);
    count_lds<<<countBlocks, 256, 0, stream>>>(col, cnt, E, n, countBlocks);
    scan_p1<<<nodeBlocks, 256, 0, stream>>>(cnt, partial, n);
    scan_p2<<<1, 256, 0, stream>>>(partial, rowPtr, n, nodeBlocks);
    scan_p3<<<nodeBlocks, 256, 0, stream>>>(cnt, partial, rowPtr, cursor, dinvp, n);
    fill_part<<<fillBlocks, 256, 0, stream>>>(row, col, cursor, srcList, E, rw);

    // ---- layer 1 ----
    gemm_nk<<<gemmBlocks, 256, 0, stream>>>(x, W1, b1, dinvp, bufA, hb, n, 0);
    agg_post<true><<<nodeWaveBlocks, 256, 0, stream>>>(bufA, (const unsigned int*)hb,
                                                       rowPtr, srcList, dinvp,
                                                       b1, g1, be1, bufB, n);
    // ---- layer 2 ----
    gemm_nk<<<gemmBlocks, 256, 0, stream>>>(bufB, W2, b2, dinvp, bufA, hb, n, 0);
    agg_post<true><<<nodeWaveBlocks, 256, 0, stream>>>(bufA, (const unsigned int*)hb,
                                                       rowPtr, srcList, dinvp,
                                                       b2, g2, be2, bufB, n);
    // ---- layer 3 (relu, no LN) ----
    gemm_nk<<<gemmBlocks, 256, 0, stream>>>(bufB, W3, b3, dinvp, bufA, hb, n, 0);
    agg_post<false><<<nodeWaveBlocks, 256, 0, stream>>>(bufA, (const unsigned int*)hb,
                                                        rowPtr, srcList, dinvp,
                                                        b3, b3, b3, bufB, n);
    // ---- MLP head ----
    gemm_nk<<<gemmBlocks, 256, 0, stream>>>(bufB, Wp1, bp1, dinvp, bufA, nullptr, n, 1);
    nhead_f32<<<nodeBlocks, 256, 0, stream>>>(bufA, Wp2, bp2, out, n);
}

// Round 3
// 543.264 us; speedup vs baseline: 1.0488x; 1.0488x over previous
//
#include <hip/hip_runtime.h>
#include <hip/hip_bf16.h>

#define EPS_LN 1e-5f
#define NCAP 51200            // node-capacity (n = 50000)
#define HALF (NCAP / 2)       // packed 16-bit pairs per slab = 25600 words (100KB)
#define NB   256              // edge chunks (= blocks for hist/fill)

typedef int ivec4 __attribute__((ext_vector_type(4)));

// ===========================================================================
// R23: atomic-free CSR build. R22 post-mortem showed fill_part's 50MB/60MB
// fabric traffic = 1.6M device-scope cursor atomics (each a fabric RMW past
// the non-coherent per-XCD L2s), not read-eviction. Replace count_lds +
// fill_part with a 2-pass LDS counting sort:
//   hist_chunk:   per-chunk LDS histogram -> coalesced slab write (no atomics)
//   chunk_prefix: packed serial prefix over chunks -> per-chunk starts + cnt
//   fill_sort:    LDS cursor slab (packed halves), pos = rowPtr[c]+prefix,
//                 only the 6.4MB srcList scatter remains. Zero global atomics.
// chunkHist (26.2MB) aliases bufA/bufB (unused until layer 1; stream-ordered).
// ===========================================================================

__global__ __launch_bounds__(256) void hist_chunk(const int* __restrict__ col,
                                                  unsigned int* __restrict__ chunkHist,
                                                  int E, int per) {
    __shared__ unsigned int hist[HALF];
    int t = threadIdx.x;
    for (int i = t; i < HALF; i += 256) hist[i] = 0;
    __syncthreads();
    int s0 = blockIdx.x * per;
    int s1 = s0 + per; if (s1 > E) s1 = E;
    for (int i = s0 + t; i < s1; i += 256) {
        int c = __builtin_nontemporal_load(col + i);
        atomicAdd(&hist[c >> 1], (c & 1) ? 65536u : 1u);
    }
    __syncthreads();
    unsigned int* dst = chunkHist + (size_t)blockIdx.x * HALF;
    for (int i = t; i < HALF; i += 256)
        __builtin_nontemporal_store(hist[i], dst + i);
}

// One thread per node-pair word: serial packed prefix across NB chunks.
// Batched 16-deep loads for memory-level parallelism (loop is latency-bound
// otherwise: 256 dependent line-misses). Packed 32-bit add is safe: each
// 16-bit half's running total = node degree << 65536.
__global__ __launch_bounds__(256) void chunk_prefix(unsigned int* __restrict__ chunkHist,
                                                    int* __restrict__ cnt, int n) {
    int w = blockIdx.x * 256 + threadIdx.x;
    if (w >= HALF) return;
    unsigned int run = 0;
    for (int b0 = 0; b0 < NB; b0 += 16) {
        unsigned int v[16];
#pragma unroll
        for (int j = 0; j < 16; j++)
            v[j] = chunkHist[(size_t)(b0 + j) * HALF + w];
#pragma unroll
        for (int j = 0; j < 16; j++) {
            unsigned int tv = v[j];
            chunkHist[(size_t)(b0 + j) * HALF + w] = run;
            run += tv;
        }
    }
    if (2 * w < n)     cnt[2 * w]     = (int)(run & 0xffffu);
    if (2 * w + 1 < n) cnt[2 * w + 1] = (int)(run >> 16);
}

__global__ __launch_bounds__(256) void scan_p1(const int* __restrict__ cnt,
                                               int* __restrict__ partial, int n) {
    __shared__ int s[256];
    int t = threadIdx.x;
    int i = blockIdx.x * 256 + t;
    s[t] = (i < n) ? cnt[i] : 0;
    __syncthreads();
    for (int st = 128; st > 0; st >>= 1) {
        if (t < st) s[t] += s[t + st];
        __syncthreads();
    }
    if (t == 0) partial[blockIdx.x] = s[0];
}

__global__ __launch_bounds__(256) void scan_p2(int* __restrict__ partial,
                                               int* __restrict__ rowPtr,
                                               int n, int nb) {
    if (threadIdx.x == 0) {
        int run = 0;
        for (int i = 0; i < nb; i++) { int v = partial[i]; partial[i] = run; run += v; }
        rowPtr[n] = run;
    }
}

__global__ __launch_bounds__(256) void scan_p3(const int* __restrict__ cnt,
                                               const int* __restrict__ partial,
                                               int* __restrict__ rowPtr,
                                               float* __restrict__ dinv, int n) {
    __shared__ int sh[256];
    int t = threadIdx.x;
    int i = blockIdx.x * 256 + t;
    int v = (i < n) ? cnt[i] : 0;
    sh[t] = v;
    __syncthreads();
    for (int d = 1; d < 256; d <<= 1) {
        int add = (t >= d) ? sh[t - d] : 0;
        __syncthreads();
        sh[t] += add;
        __syncthreads();
    }
    if (i < n) {
        int excl = sh[t] - v + partial[blockIdx.x];
        rowPtr[i] = excl;
        dinv[i] = rsqrtf((float)v + 1.0f);   // +1 self-loop
    }
}

// Chunk b: LDS cursor slab initialized to per-chunk prefix (packed halves).
// LDS atomicAdd returns the packed old -> extract this edge's within-node
// rank; pos = rowPtr[c] + rank. srcList scatter is the only global write.
__global__ __launch_bounds__(256) void fill_sort(const int* __restrict__ row,
                                                 const int* __restrict__ col,
                                                 const unsigned int* __restrict__ chunkPre,
                                                 const int* __restrict__ rowPtr,
                                                 int* __restrict__ srcList,
                                                 int E, int per) {
    __shared__ unsigned int curs[HALF];
    int t = threadIdx.x;
    const unsigned int* src = chunkPre + (size_t)blockIdx.x * HALF;
    for (int i = t; i < HALF; i += 256)
        curs[i] = __builtin_nontemporal_load(src + i);
    __syncthreads();
    int s0 = blockIdx.x * per;
    int s1 = s0 + per; if (s1 > E) s1 = E;
    for (int i = s0 + t; i < s1; i += 256) {
        int c = __builtin_nontemporal_load(col + i);
        int r = __builtin_nontemporal_load(row + i);
        unsigned int old = atomicAdd(&curs[c >> 1], (c & 1) ? 65536u : 1u);
        unsigned int off = (c & 1) ? (old >> 16) : (old & 0xffffu);
        srcList[rowPtr[c] + (int)off] = r;
    }
}

// ---------------------------------------------------------------------------
// Tiled GEMM: 128x128 block tile, 256 threads, 8x8 per thread, BK=16.
// ---------------------------------------------------------------------------
__global__ __launch_bounds__(256) void gemm_nk(const float* __restrict__ A,
                                               const float* __restrict__ W,
                                               const float* __restrict__ bias,
                                               const float* __restrict__ dinv,
                                               float* __restrict__ C,
                                               unsigned short* __restrict__ Cb,
                                               int n, int addb) {
    __shared__ float As[128][17];
    __shared__ float Ws[16][128];

    const int tx = threadIdx.x;
    const int row0 = blockIdx.x * 128;
    const int jg = (tx & 15) * 8;
    const int ig = (tx >> 4) * 8;

    float acc[8][8];
#pragma unroll
    for (int r = 0; r < 8; r++)
#pragma unroll
        for (int c = 0; c < 8; c++) acc[r][c] = 0.f;

    for (int k0 = 0; k0 < 128; k0 += 16) {
        {
#pragma unroll
            for (int q = 0; q < 2; q++) {
                int f = tx * 2 + q;
                int r = f >> 2;
                int c4 = (f & 3) * 4;
                int grow = row0 + r;
                float4 v = make_float4(0.f, 0.f, 0.f, 0.f);
                if (grow < n) v = *(const float4*)(A + (size_t)grow * 128 + k0 + c4);
                As[r][c4 + 0] = v.x; As[r][c4 + 1] = v.y;
                As[r][c4 + 2] = v.z; As[r][c4 + 3] = v.w;
            }
        }
        {
#pragma unroll
            for (int q = 0; q < 2; q++) {
                int f = tx * 2 + q;
                int kr = f >> 5;
                int c4 = (f & 31) * 4;
                *(float4*)&Ws[kr][c4] = *(const float4*)(W + (size_t)(k0 + kr) * 128 + c4);
            }
        }
        __syncthreads();
#pragma unroll
        for (int kk = 0; kk < 16; kk++) {
            float4 w0 = *(const float4*)&Ws[kk][jg];
            float4 w1 = *(const float4*)&Ws[kk][jg + 4];
            float wv[8] = {w0.x, w0.y, w0.z, w0.w, w1.x, w1.y, w1.z, w1.w};
#pragma unroll
            for (int r = 0; r < 8; r++) {
                float a = As[ig + r][kk];
#pragma unroll
                for (int c = 0; c < 8; c++) acc[r][c] += a * wv[c];
            }
        }
        __syncthreads();
    }

    float bv[8] = {0.f, 0.f, 0.f, 0.f, 0.f, 0.f, 0.f, 0.f};
    if (addb) {
        float4 b0 = *(const float4*)(bias + jg);
        float4 b1 = *(const float4*)(bias + jg + 4);
        bv[0] = b0.x; bv[1] = b0.y; bv[2] = b0.z; bv[3] = b0.w;
        bv[4] = b1.x; bv[5] = b1.y; bv[6] = b1.z; bv[7] = b1.w;
    }
#pragma unroll
    for (int r = 0; r < 8; r++) {
        int grow = row0 + ig + r;
        if (grow < n) {
            float o[8];
#pragma unroll
            for (int c = 0; c < 8; c++) o[c] = acc[r][c] + bv[c];
            *(float4*)(C + (size_t)grow * 128 + jg)     = make_float4(o[0], o[1], o[2], o[3]);
            *(float4*)(C + (size_t)grow * 128 + jg + 4) = make_float4(o[4], o[5], o[6], o[7]);
            if (Cb) {
                float dr = dinv[grow];
                ushort4 u0, u1;
                __hip_bfloat16 t;
                t = __float2bfloat16(o[0] * dr); u0.x = *(unsigned short*)&t;
                t = __float2bfloat16(o[1] * dr); u0.y = *(unsigned short*)&t;
                t = __float2bfloat16(o[2] * dr); u0.z = *(unsigned short*)&t;
                t = __float2bfloat16(o[3] * dr); u0.w = *(unsigned short*)&t;
                t = __float2bfloat16(o[4] * dr); u1.x = *(unsigned short*)&t;
                t = __float2bfloat16(o[5] * dr); u1.y = *(unsigned short*)&t;
                t = __float2bfloat16(o[6] * dr); u1.z = *(unsigned short*)&t;
                t = __float2bfloat16(o[7] * dr); u1.w = *(unsigned short*)&t;
                *(ushort4*)(Cb + (size_t)grow * 128 + jg)     = u0;
                *(ushort4*)(Cb + (size_t)grow * 128 + jg + 4) = u1;
            }
        }
    }
}

// ---------------------------------------------------------------------------
// Fused gather (bf16 pre-scaled) + self-loop(f32) + bias + relu (+ LN).
// ---------------------------------------------------------------------------
template<bool DO_LN>
__global__ __launch_bounds__(256) void agg_post(const float* __restrict__ h,
                                                const unsigned int* __restrict__ hb,
                                                const int* __restrict__ rowPtr,
                                                const int* __restrict__ srcList,
                                                const float* __restrict__ dinv,
                                                const float* __restrict__ b,
                                                const float* __restrict__ g,
                                                const float* __restrict__ beta,
                                                float* __restrict__ out, int n) {
    int wid = (blockIdx.x * 256 + threadIdx.x) >> 6;
    int lane = threadIdx.x & 63;
    if (wid >= n) return;
    int e0 = rowPtr[wid], e1 = rowPtr[wid + 1];
    float dc = dinv[wid];
    size_t base = (size_t)wid * 128 + lane * 2;
    float2 hs = *(const float2*)(h + base);
    float ax = hs.x * dc * dc;
    float ay = hs.y * dc * dc;

    int e = e0;
    for (; e + 8 <= e1; e += 8) {
        int r0 = srcList[e + 0], r1 = srcList[e + 1];
        int r2 = srcList[e + 2], r3 = srcList[e + 3];
        int r4 = srcList[e + 4], r5 = srcList[e + 5];
        int r6 = srcList[e + 6], r7 = srcList[e + 7];
        unsigned int u0 = hb[(size_t)r0 * 64 + lane];
        unsigned int u1 = hb[(size_t)r1 * 64 + lane];
        unsigned int u2 = hb[(size_t)r2 * 64 + lane];
        unsigned int u3 = hb[(size_t)r3 * 64 + lane];
        unsigned int u4 = hb[(size_t)r4 * 64 + lane];
        unsigned int u5 = hb[(size_t)r5 * 64 + lane];
        unsigned int u6 = hb[(size_t)r6 * 64 + lane];
        unsigned int u7 = hb[(size_t)r7 * 64 + lane];
        ax += __uint_as_float(u0 << 16) * dc;  ay += __uint_as_float(u0 & 0xffff0000u) * dc;
        ax += __uint_as_float(u1 << 16) * dc;  ay += __uint_as_float(u1 & 0xffff0000u) * dc;
        ax += __uint_as_float(u2 << 16) * dc;  ay += __uint_as_float(u2 & 0xffff0000u) * dc;
        ax += __uint_as_float(u3 << 16) * dc;  ay += __uint_as_float(u3 & 0xffff0000u) * dc;
        ax += __uint_as_float(u4 << 16) * dc;  ay += __uint_as_float(u4 & 0xffff0000u) * dc;
        ax += __uint_as_float(u5 << 16) * dc;  ay += __uint_as_float(u5 & 0xffff0000u) * dc;
        ax += __uint_as_float(u6 << 16) * dc;  ay += __uint_as_float(u6 & 0xffff0000u) * dc;
        ax += __uint_as_float(u7 << 16) * dc;  ay += __uint_as_float(u7 & 0xffff0000u) * dc;
    }
    for (; e < e1; e++) {
        int r = srcList[e];
        unsigned int u = hb[(size_t)r * 64 + lane];
        ax += __uint_as_float(u << 16) * dc;
        ay += __uint_as_float(u & 0xffff0000u) * dc;
    }

    ax = fmaxf(ax + b[lane * 2 + 0], 0.f);
    ay = fmaxf(ay + b[lane * 2 + 1], 0.f);
    if (DO_LN) {
        float s = ax + ay;
#pragma unroll
        for (int m = 32; m >= 1; m >>= 1) s += __shfl_xor(s, m, 64);
        float mu = s * (1.f / 128.f);
        float dx = ax - mu, dy = ay - mu;
        float sq = dx * dx + dy * dy;
#pragma unroll
        for (int m = 32; m >= 1; m >>= 1) sq += __shfl_xor(sq, m, 64);
        float rs = rsqrtf(sq * (1.f / 128.f) + EPS_LN);
        ax = dx * rs * g[lane * 2 + 0] + beta[lane * 2 + 0];
        ay = dy * rs * g[lane * 2 + 1] + beta[lane * 2 + 1];
    }
    *(float2*)(out + base) = make_float2(ax, ay);
}

// ---------------------------------------------------------------------------
__global__ __launch_bounds__(256) void nhead_f32(const float* __restrict__ hp,
                                                 const float* __restrict__ W,
                                                 const float* __restrict__ b,
                                                 float* __restrict__ out, int n) {
    __shared__ float Ws[384];
    int t = threadIdx.x;
    if (t < 192) { Ws[t] = W[t]; Ws[t + 192] = W[t + 192]; }
    __syncthreads();
    int i = blockIdx.x * 256 + t;
    if (i >= n) return;
    float p0 = b[0], p1 = b[1], p2 = b[2];
    const float4* h4 = (const float4*)(hp + (size_t)i * 128);
#pragma unroll
    for (int k4 = 0; k4 < 32; k4++) {
        float4 v = h4[k4];
        const float* w = &Ws[k4 * 12];
        p0 += v.x * w[0] + v.y * w[3] + v.z * w[6] + v.w * w[9];
        p1 += v.x * w[1] + v.y * w[4] + v.z * w[7] + v.w * w[10];
        p2 += v.x * w[2] + v.y * w[5] + v.z * w[8] + v.w * w[11];
    }
    out[(size_t)i * 3 + 0] = p0;
    out[(size_t)i * 3 + 1] = p1;
    out[(size_t)i * 3 + 2] = p2;
}

// ---------------------------------------------------------------------------
extern "C" void kernel_launch(void* const* d_in, const int* in_sizes, int n_in,
                              void* d_out, int out_size, void* d_ws, size_t ws_size,
                              hipStream_t stream) {
    const float* x   = (const float*)d_in[0];
    const int* ei    = (const int*)d_in[1];
    const float* W1  = (const float*)d_in[2];
    const float* b1  = (const float*)d_in[3];
    const float* W2  = (const float*)d_in[4];
    const float* b2  = (const float*)d_in[5];
    const float* W3  = (const float*)d_in[6];
    const float* b3  = (const float*)d_in[7];
    const float* g1  = (const float*)d_in[8];
    const float* be1 = (const float*)d_in[9];
    const float* g2  = (const float*)d_in[10];
    const float* be2 = (const float*)d_in[11];
    const float* Wp1 = (const float*)d_in[12];
    const float* bp1 = (const float*)d_in[13];
    const float* Wp2 = (const float*)d_in[14];
    const float* bp2 = (const float*)d_in[15];
    float* out = (float*)d_out;

    const int n = in_sizes[0] / 128;   // 50000
    const int E = in_sizes[1] / 2;     // 1600000
    const int* row = ei;
    const int* col = ei + E;

    char* ws = (char*)d_ws;
    size_t nA  = ((size_t)n * 4 + 255) & ~(size_t)255;
    size_t nA1 = ((size_t)(n + 1) * 4 + 255) & ~(size_t)255;
    size_t eA  = ((size_t)E * 4 + 255) & ~(size_t)255;
    size_t hbA = ((size_t)n * 128 * 2 + 255) & ~(size_t)255;
    int*   cnt     = (int*)ws;
    int*   rowPtr  = (int*)(ws + nA);
    float* dinvp   = (float*)(ws + nA + nA1);
    int*   partial = (int*)(ws + 2 * nA + nA1);
    int*   srcList = (int*)(ws + 3 * nA + nA1);
    unsigned short* hb = (unsigned short*)(ws + 3 * nA + nA1 + eA);
    float* bufA    = (float*)(ws + 3 * nA + nA1 + eA + hbA);
    float* bufB    = bufA + (size_t)n * 128;
    // chunkHist (NB*HALF*4 = 26.2MB) aliases bufA/bufB (51.2MB): consumed by
    // fill_sort before the first gemm writes bufA (same-stream ordering).
    unsigned int* chunkHist = (unsigned int*)bufA;

    const int gemmBlocks = (n + 127) / 128;
    const int nodeWaveBlocks = (n + 3) / 4;
    const int nodeBlocks = (n + 255) / 256;
    const int per = (E + NB - 1) / NB;           // 6250 edges/chunk
    const int prefBlocks = (HALF + 255) / 256;   // 100

    // CSR build (atomic-free counting sort)
    hist_chunk<<<NB, 256, 0, stream>>>(col, chunkHist, E, per);
    chunk_prefix<<<prefBlocks, 256, 0, stream>>>(chunkHist, cnt, n);
    scan_p1<<<nodeBlocks, 256, 0, stream>>>(cnt, partial, n);
    scan_p2<<<1, 256, 0, stream>>>(partial, rowPtr, n, nodeBlocks);
    scan_p3<<<nodeBlocks, 256, 0, stream>>>(cnt, partial, rowPtr, dinvp, n);
    fill_sort<<<NB, 256, 0, stream>>>(row, col, chunkHist, rowPtr, srcList, E, per);

    // ---- layer 1 ----
    gemm_nk<<<gemmBlocks, 256, 0, stream>>>(x, W1, b1, dinvp, bufA, hb, n, 0);
    agg_post<true><<<nodeWaveBlocks, 256, 0, stream>>>(bufA, (const unsigned int*)hb,
                                                       rowPtr, srcList, dinvp,
                                                       b1, g1, be1, bufB, n);
    // ---- layer 2 ----
    gemm_nk<<<gemmBlocks, 256, 0, stream>>>(bufB, W2, b2, dinvp, bufA, hb, n, 0);
    agg_post<true><<<nodeWaveBlocks, 256, 0, stream>>>(bufA, (const unsigned int*)hb,
                                                       rowPtr, srcList, dinvp,
                                                       b2, g2, be2, bufB, n);
    // ---- layer 3 (relu, no LN) ----
    gemm_nk<<<gemmBlocks, 256, 0, stream>>>(bufB, W3, b3, dinvp, bufA, hb, n, 0);
    agg_post<false><<<nodeWaveBlocks, 256, 0, stream>>>(bufA, (const unsigned int*)hb,
                                                        rowPtr, srcList, dinvp,
                                                        b3, b3, b3, bufB, n);
    // ---- MLP head ----
    gemm_nk<<<gemmBlocks, 256, 0, stream>>>(bufB, Wp1, bp1, dinvp, bufA, nullptr, n, 1);
    nhead_f32<<<nodeBlocks, 256, 0, stream>>>(bufA, Wp2, bp2, out, n);
}

// Round 4
// 470.888 us; speedup vs baseline: 1.2100x; 1.1537x over previous
//
#include <hip/hip_runtime.h>
#include <hip/hip_bf16.h>

#define EPS_LN 1e-5f
#define NB    256             // edge chunks for hist/scatter
#define SEGCAP 16384          // srcList segment capacity per bucket (64KB LDS)

typedef int ivec4 __attribute__((ext_vector_type(4)));

// ===========================================================================
// R24: bucketed counting sort for the CSR build. R23 post-mortem: srcList's
// 9.6x write amplification = cross-XCD partial-line writeback (every 64B line
// dirtied by scatter writes from all 8 XCDs' L2s). Fix: single-owner writes.
//   bucket_hist:   per-chunk histogram over 196 node-buckets (bucket=c>>8)
//   bucket_scan:   per-(chunk,bucket) starts + bucketStart + rowPtr[n]
//   scatter_pairs: (c,r) pairs -> bucket-major tmp; run-sequential writes
//                  (~25-edge runs/chunk/bucket -> line owned by <=2 chunks)
//   bucket_fill:   one block per bucket: per-node count -> in-block scan
//                  (emits rowPtr+dinv; scan_p1..p3 deleted) -> LDS-staged
//                  srcList segment, coalesced flush. One block per line.
// tmp/chunkBH/bucketStart alias bufA (consumed before layer-1 gemm).
// ===========================================================================

__global__ __launch_bounds__(256) void bucket_hist(const int* __restrict__ col,
                                                   int* __restrict__ chunkBH,
                                                   int E, int per, int nbuck) {
    __shared__ int hist[256];
    int t = threadIdx.x;
    hist[t] = 0;
    __syncthreads();
    int s0 = blockIdx.x * per;
    int s1 = s0 + per; if (s1 > E) s1 = E;
    if (s0 < s1) {
        int q0 = s0 >> 2, q1 = s1 >> 2;
        for (int i = q0 + t; i < q1; i += 256) {
            ivec4 c = __builtin_nontemporal_load((const ivec4*)col + i);
            atomicAdd(&hist[c.x >> 8], 1);
            atomicAdd(&hist[c.y >> 8], 1);
            atomicAdd(&hist[c.z >> 8], 1);
            atomicAdd(&hist[c.w >> 8], 1);
        }
        for (int i = (q1 << 2) + t; i < s1; i += 256)
            atomicAdd(&hist[col[i] >> 8], 1);
    }
    __syncthreads();
    if (t < nbuck) chunkBH[blockIdx.x * 256 + t] = hist[t];   // [k][b], coalesced
}

// One thread per bucket: serial prefix over chunks (batched 16-deep,
// coalesced across threads), then block-scan of bucket totals.
__global__ __launch_bounds__(256) void bucket_scan(int* __restrict__ chunkBH,
                                                   int* __restrict__ bucketStart,
                                                   int* __restrict__ rowPtr,
                                                   int E, int n, int nbuck, int nb) {
    __shared__ int tot[256];
    int t = threadIdx.x;
    int run = 0;
    if (t < nbuck) {
        for (int k0 = 0; k0 < nb; k0 += 16) {
            int v[16];
#pragma unroll
            for (int j = 0; j < 16; j++)
                v[j] = (k0 + j < nb) ? chunkBH[(k0 + j) * 256 + t] : 0;
#pragma unroll
            for (int j = 0; j < 16; j++) {
                int tv = v[j];
                if (k0 + j < nb) chunkBH[(k0 + j) * 256 + t] = run;
                run += tv;
            }
        }
    }
    tot[t] = run;
    __syncthreads();
    for (int d = 1; d < 256; d <<= 1) {
        int add = (t >= d) ? tot[t - d] : 0;
        __syncthreads();
        tot[t] += add;
        __syncthreads();
    }
    if (t < nbuck) bucketStart[t] = tot[t] - run;
    if (t == 0) { bucketStart[nbuck] = E; rowPtr[n] = E; }
}

__global__ __launch_bounds__(256) void scatter_pairs(const int* __restrict__ row,
                                                     const int* __restrict__ col,
                                                     const int* __restrict__ chunkBH,
                                                     const int* __restrict__ bucketStart,
                                                     unsigned long long* __restrict__ tmp,
                                                     int E, int per, int nbuck) {
    __shared__ int curs[256];
    int t = threadIdx.x;
    int k = blockIdx.x;
    curs[t] = (t < nbuck) ? (chunkBH[k * 256 + t] + bucketStart[t]) : 0;
    __syncthreads();
    int s0 = k * per;
    int s1 = s0 + per; if (s1 > E) s1 = E;
    if (s0 >= s1) return;
    int q0 = s0 >> 2, q1 = s1 >> 2;
    for (int i = q0 + t; i < q1; i += 256) {
        ivec4 c4 = __builtin_nontemporal_load((const ivec4*)col + i);
        ivec4 r4 = __builtin_nontemporal_load((const ivec4*)row + i);
        int p0 = atomicAdd(&curs[c4.x >> 8], 1);
        tmp[p0] = ((unsigned long long)(unsigned)c4.x << 32) | (unsigned)r4.x;
        int p1 = atomicAdd(&curs[c4.y >> 8], 1);
        tmp[p1] = ((unsigned long long)(unsigned)c4.y << 32) | (unsigned)r4.y;
        int p2 = atomicAdd(&curs[c4.z >> 8], 1);
        tmp[p2] = ((unsigned long long)(unsigned)c4.z << 32) | (unsigned)r4.z;
        int p3 = atomicAdd(&curs[c4.w >> 8], 1);
        tmp[p3] = ((unsigned long long)(unsigned)c4.w << 32) | (unsigned)r4.w;
    }
    for (int i = (q1 << 2) + t; i < s1; i += 256) {
        int c = col[i], r = row[i];
        int p = atomicAdd(&curs[c >> 8], 1);
        tmp[p] = ((unsigned long long)(unsigned)c << 32) | (unsigned)r;
    }
}

// One block per bucket (256 nodes). Pass 1: per-node counts -> block scan ->
// rowPtr + dinv. Pass 2: place srcList segment in LDS via LDS cursors, then
// coalesced flush — each srcList line written by exactly one block.
__global__ __launch_bounds__(256) void bucket_fill(const unsigned long long* __restrict__ tmp,
                                                   const int* __restrict__ bucketStart,
                                                   int* __restrict__ rowPtr,
                                                   float* __restrict__ dinv,
                                                   int* __restrict__ srcList,
                                                   int n) {
    __shared__ int cnt[256];
    __shared__ int cur[256];
    __shared__ int seg[SEGCAP];
    int b = blockIdx.x, t = threadIdx.x;
    int node0 = b << 8;
    int s0 = bucketStart[b], s1 = bucketStart[b + 1];
    int len = s1 - s0;
    cnt[t] = 0;
    __syncthreads();
    for (int i = s0 + t; i < s1; i += 256) {
        int c = (int)(tmp[i] >> 32);
        atomicAdd(&cnt[c - node0], 1);
    }
    __syncthreads();
    int v = cnt[t];
    cur[t] = v;
    __syncthreads();
    for (int d = 1; d < 256; d <<= 1) {
        int add = (t >= d) ? cur[t - d] : 0;
        __syncthreads();
        cur[t] += add;
        __syncthreads();
    }
    int excl = cur[t] - v;
    int node = node0 + t;
    if (node < n) {
        rowPtr[node] = s0 + excl;
        dinv[node] = rsqrtf((float)v + 1.0f);   // +1 self-loop
    }
    cur[t] = excl;
    __syncthreads();
    if (len <= SEGCAP) {
        for (int i = s0 + t; i < s1; i += 256) {
            unsigned long long p = tmp[i];
            int c = (int)(p >> 32);
            int r = (int)(p & 0xffffffffu);
            int pos = atomicAdd(&cur[c - node0], 1);
            seg[pos] = r;
        }
        __syncthreads();
        for (int i = t; i < len; i += 256)
            srcList[s0 + i] = seg[i];
    } else {                                    // overflow fallback (never for this graph)
        for (int i = s0 + t; i < s1; i += 256) {
            unsigned long long p = tmp[i];
            int c = (int)(p >> 32);
            int r = (int)(p & 0xffffffffu);
            int pos = atomicAdd(&cur[c - node0], 1);
            srcList[s0 + pos] = r;
        }
    }
}

// ---------------------------------------------------------------------------
// Tiled GEMM: 128x128 block tile, 256 threads, 8x8 per thread, BK=16.
// ---------------------------------------------------------------------------
__global__ __launch_bounds__(256) void gemm_nk(const float* __restrict__ A,
                                               const float* __restrict__ W,
                                               const float* __restrict__ bias,
                                               const float* __restrict__ dinv,
                                               float* __restrict__ C,
                                               unsigned short* __restrict__ Cb,
                                               int n, int addb) {
    __shared__ float As[128][17];
    __shared__ float Ws[16][128];

    const int tx = threadIdx.x;
    const int row0 = blockIdx.x * 128;
    const int jg = (tx & 15) * 8;
    const int ig = (tx >> 4) * 8;

    float acc[8][8];
#pragma unroll
    for (int r = 0; r < 8; r++)
#pragma unroll
        for (int c = 0; c < 8; c++) acc[r][c] = 0.f;

    for (int k0 = 0; k0 < 128; k0 += 16) {
        {
#pragma unroll
            for (int q = 0; q < 2; q++) {
                int f = tx * 2 + q;
                int r = f >> 2;
                int c4 = (f & 3) * 4;
                int grow = row0 + r;
                float4 v = make_float4(0.f, 0.f, 0.f, 0.f);
                if (grow < n) v = *(const float4*)(A + (size_t)grow * 128 + k0 + c4);
                As[r][c4 + 0] = v.x; As[r][c4 + 1] = v.y;
                As[r][c4 + 2] = v.z; As[r][c4 + 3] = v.w;
            }
        }
        {
#pragma unroll
            for (int q = 0; q < 2; q++) {
                int f = tx * 2 + q;
                int kr = f >> 5;
                int c4 = (f & 31) * 4;
                *(float4*)&Ws[kr][c4] = *(const float4*)(W + (size_t)(k0 + kr) * 128 + c4);
            }
        }
        __syncthreads();
#pragma unroll
        for (int kk = 0; kk < 16; kk++) {
            float4 w0 = *(const float4*)&Ws[kk][jg];
            float4 w1 = *(const float4*)&Ws[kk][jg + 4];
            float wv[8] = {w0.x, w0.y, w0.z, w0.w, w1.x, w1.y, w1.z, w1.w};
#pragma unroll
            for (int r = 0; r < 8; r++) {
                float a = As[ig + r][kk];
#pragma unroll
                for (int c = 0; c < 8; c++) acc[r][c] += a * wv[c];
            }
        }
        __syncthreads();
    }

    float bv[8] = {0.f, 0.f, 0.f, 0.f, 0.f, 0.f, 0.f, 0.f};
    if (addb) {
        float4 b0 = *(const float4*)(bias + jg);
        float4 b1 = *(const float4*)(bias + jg + 4);
        bv[0] = b0.x; bv[1] = b0.y; bv[2] = b0.z; bv[3] = b0.w;
        bv[4] = b1.x; bv[5] = b1.y; bv[6] = b1.z; bv[7] = b1.w;
    }
#pragma unroll
    for (int r = 0; r < 8; r++) {
        int grow = row0 + ig + r;
        if (grow < n) {
            float o[8];
#pragma unroll
            for (int c = 0; c < 8; c++) o[c] = acc[r][c] + bv[c];
            *(float4*)(C + (size_t)grow * 128 + jg)     = make_float4(o[0], o[1], o[2], o[3]);
            *(float4*)(C + (size_t)grow * 128 + jg + 4) = make_float4(o[4], o[5], o[6], o[7]);
            if (Cb) {
                float dr = dinv[grow];
                ushort4 u0, u1;
                __hip_bfloat16 t;
                t = __float2bfloat16(o[0] * dr); u0.x = *(unsigned short*)&t;
                t = __float2bfloat16(o[1] * dr); u0.y = *(unsigned short*)&t;
                t = __float2bfloat16(o[2] * dr); u0.z = *(unsigned short*)&t;
                t = __float2bfloat16(o[3] * dr); u0.w = *(unsigned short*)&t;
                t = __float2bfloat16(o[4] * dr); u1.x = *(unsigned short*)&t;
                t = __float2bfloat16(o[5] * dr); u1.y = *(unsigned short*)&t;
                t = __float2bfloat16(o[6] * dr); u1.z = *(unsigned short*)&t;
                t = __float2bfloat16(o[7] * dr); u1.w = *(unsigned short*)&t;
                *(ushort4*)(Cb + (size_t)grow * 128 + jg)     = u0;
                *(ushort4*)(Cb + (size_t)grow * 128 + jg + 4) = u1;
            }
        }
    }
}

// ---------------------------------------------------------------------------
// Fused gather (bf16 pre-scaled) + self-loop(f32) + bias + relu (+ LN).
// ---------------------------------------------------------------------------
template<bool DO_LN>
__global__ __launch_bounds__(256) void agg_post(const float* __restrict__ h,
                                                const unsigned int* __restrict__ hb,
                                                const int* __restrict__ rowPtr,
                                                const int* __restrict__ srcList,
                                                const float* __restrict__ dinv,
                                                const float* __restrict__ b,
                                                const float* __restrict__ g,
                                                const float* __restrict__ beta,
                                                float* __restrict__ out, int n) {
    int wid = (blockIdx.x * 256 + threadIdx.x) >> 6;
    int lane = threadIdx.x & 63;
    if (wid >= n) return;
    int e0 = rowPtr[wid], e1 = rowPtr[wid + 1];
    float dc = dinv[wid];
    size_t base = (size_t)wid * 128 + lane * 2;
    float2 hs = *(const float2*)(h + base);
    float ax = hs.x * dc * dc;
    float ay = hs.y * dc * dc;

    int e = e0;
    for (; e + 8 <= e1; e += 8) {
        int r0 = srcList[e + 0], r1 = srcList[e + 1];
        int r2 = srcList[e + 2], r3 = srcList[e + 3];
        int r4 = srcList[e + 4], r5 = srcList[e + 5];
        int r6 = srcList[e + 6], r7 = srcList[e + 7];
        unsigned int u0 = hb[(size_t)r0 * 64 + lane];
        unsigned int u1 = hb[(size_t)r1 * 64 + lane];
        unsigned int u2 = hb[(size_t)r2 * 64 + lane];
        unsigned int u3 = hb[(size_t)r3 * 64 + lane];
        unsigned int u4 = hb[(size_t)r4 * 64 + lane];
        unsigned int u5 = hb[(size_t)r5 * 64 + lane];
        unsigned int u6 = hb[(size_t)r6 * 64 + lane];
        unsigned int u7 = hb[(size_t)r7 * 64 + lane];
        ax += __uint_as_float(u0 << 16) * dc;  ay += __uint_as_float(u0 & 0xffff0000u) * dc;
        ax += __uint_as_float(u1 << 16) * dc;  ay += __uint_as_float(u1 & 0xffff0000u) * dc;
        ax += __uint_as_float(u2 << 16) * dc;  ay += __uint_as_float(u2 & 0xffff0000u) * dc;
        ax += __uint_as_float(u3 << 16) * dc;  ay += __uint_as_float(u3 & 0xffff0000u) * dc;
        ax += __uint_as_float(u4 << 16) * dc;  ay += __uint_as_float(u4 & 0xffff0000u) * dc;
        ax += __uint_as_float(u5 << 16) * dc;  ay += __uint_as_float(u5 & 0xffff0000u) * dc;
        ax += __uint_as_float(u6 << 16) * dc;  ay += __uint_as_float(u6 & 0xffff0000u) * dc;
        ax += __uint_as_float(u7 << 16) * dc;  ay += __uint_as_float(u7 & 0xffff0000u) * dc;
    }
    for (; e < e1; e++) {
        int r = srcList[e];
        unsigned int u = hb[(size_t)r * 64 + lane];
        ax += __uint_as_float(u << 16) * dc;
        ay += __uint_as_float(u & 0xffff0000u) * dc;
    }

    ax = fmaxf(ax + b[lane * 2 + 0], 0.f);
    ay = fmaxf(ay + b[lane * 2 + 1], 0.f);
    if (DO_LN) {
        float s = ax + ay;
#pragma unroll
        for (int m = 32; m >= 1; m >>= 1) s += __shfl_xor(s, m, 64);
        float mu = s * (1.f / 128.f);
        float dx = ax - mu, dy = ay - mu;
        float sq = dx * dx + dy * dy;
#pragma unroll
        for (int m = 32; m >= 1; m >>= 1) sq += __shfl_xor(sq, m, 64);
        float rs = rsqrtf(sq * (1.f / 128.f) + EPS_LN);
        ax = dx * rs * g[lane * 2 + 0] + beta[lane * 2 + 0];
        ay = dy * rs * g[lane * 2 + 1] + beta[lane * 2 + 1];
    }
    *(float2*)(out + base) = make_float2(ax, ay);
}

// ---------------------------------------------------------------------------
__global__ __launch_bounds__(256) void nhead_f32(const float* __restrict__ hp,
                                                 const float* __restrict__ W,
                                                 const float* __restrict__ b,
                                                 float* __restrict__ out, int n) {
    __shared__ float Ws[384];
    int t = threadIdx.x;
    if (t < 192) { Ws[t] = W[t]; Ws[t + 192] = W[t + 192]; }
    __syncthreads();
    int i = blockIdx.x * 256 + t;
    if (i >= n) return;
    float p0 = b[0], p1 = b[1], p2 = b[2];
    const float4* h4 = (const float4*)(hp + (size_t)i * 128);
#pragma unroll
    for (int k4 = 0; k4 < 32; k4++) {
        float4 v = h4[k4];
        const float* w = &Ws[k4 * 12];
        p0 += v.x * w[0] + v.y * w[3] + v.z * w[6] + v.w * w[9];
        p1 += v.x * w[1] + v.y * w[4] + v.z * w[7] + v.w * w[10];
        p2 += v.x * w[2] + v.y * w[5] + v.z * w[8] + v.w * w[11];
    }
    out[(size_t)i * 3 + 0] = p0;
    out[(size_t)i * 3 + 1] = p1;
    out[(size_t)i * 3 + 2] = p2;
}

// ---------------------------------------------------------------------------
extern "C" void kernel_launch(void* const* d_in, const int* in_sizes, int n_in,
                              void* d_out, int out_size, void* d_ws, size_t ws_size,
                              hipStream_t stream) {
    const float* x   = (const float*)d_in[0];
    const int* ei    = (const int*)d_in[1];
    const float* W1  = (const float*)d_in[2];
    const float* b1  = (const float*)d_in[3];
    const float* W2  = (const float*)d_in[4];
    const float* b2  = (const float*)d_in[5];
    const float* W3  = (const float*)d_in[6];
    const float* b3  = (const float*)d_in[7];
    const float* g1  = (const float*)d_in[8];
    const float* be1 = (const float*)d_in[9];
    const float* g2  = (const float*)d_in[10];
    const float* be2 = (const float*)d_in[11];
    const float* Wp1 = (const float*)d_in[12];
    const float* bp1 = (const float*)d_in[13];
    const float* Wp2 = (const float*)d_in[14];
    const float* bp2 = (const float*)d_in[15];
    float* out = (float*)d_out;

    const int n = in_sizes[0] / 128;   // 50000
    const int E = in_sizes[1] / 2;     // 1600000
    const int* row = ei;
    const int* col = ei + E;

    char* ws = (char*)d_ws;
    size_t nA  = ((size_t)n * 4 + 255) & ~(size_t)255;
    size_t nA1 = ((size_t)(n + 1) * 4 + 255) & ~(size_t)255;
    size_t eA  = ((size_t)E * 4 + 255) & ~(size_t)255;
    size_t hbA = ((size_t)n * 128 * 2 + 255) & ~(size_t)255;
    int*   rowPtr  = (int*)ws;
    float* dinvp   = (float*)(ws + nA1);
    int*   srcList = (int*)(ws + nA1 + nA);
    unsigned short* hb = (unsigned short*)(ws + nA1 + nA + eA);
    float* bufA    = (float*)(ws + nA1 + nA + eA + hbA);
    float* bufB    = bufA + (size_t)n * 128;
    // CSR scratch aliases bufA (25.6MB; consumed before layer-1 gemm):
    //   tmp pairs 12.8MB, chunkBH 256KB, bucketStart ~1KB
    unsigned long long* tmp = (unsigned long long*)bufA;
    int* chunkBH    = (int*)((char*)bufA + 2 * eA);
    int* bucketStart = (int*)((char*)bufA + 2 * eA + (size_t)NB * 256 * 4);

    const int nbuck = (n + 255) >> 8;                 // 196
    const int per   = (((E + NB - 1) / NB) + 15) & ~15;  // 16-aligned chunk size
    const int gemmBlocks = (n + 127) / 128;
    const int nodeWaveBlocks = (n + 3) / 4;
    const int nodeBlocks = (n + 255) / 256;

    // CSR build (bucketed counting sort, zero global atomics)
    bucket_hist<<<NB, 256, 0, stream>>>(col, chunkBH, E, per, nbuck);
    bucket_scan<<<1, 256, 0, stream>>>(chunkBH, bucketStart, rowPtr, E, n, nbuck, NB);
    scatter_pairs<<<NB, 256, 0, stream>>>(row, col, chunkBH, bucketStart, tmp, E, per, nbuck);
    bucket_fill<<<nbuck, 256, 0, stream>>>(tmp, bucketStart, rowPtr, dinvp, srcList, n);

    // ---- layer 1 ----
    gemm_nk<<<gemmBlocks, 256, 0, stream>>>(x, W1, b1, dinvp, bufA, hb, n, 0);
    agg_post<true><<<nodeWaveBlocks, 256, 0, stream>>>(bufA, (const unsigned int*)hb,
                                                       rowPtr, srcList, dinvp,
                                                       b1, g1, be1, bufB, n);
    // ---- layer 2 ----
    gemm_nk<<<gemmBlocks, 256, 0, stream>>>(bufB, W2, b2, dinvp, bufA, hb, n, 0);
    agg_post<true><<<nodeWaveBlocks, 256, 0, stream>>>(bufA, (const unsigned int*)hb,
                                                       rowPtr, srcList, dinvp,
                                                       b2, g2, be2, bufB, n);
    // ---- layer 3 (relu, no LN) ----
    gemm_nk<<<gemmBlocks, 256, 0, stream>>>(bufB, W3, b3, dinvp, bufA, hb, n, 0);
    agg_post<false><<<nodeWaveBlocks, 256, 0, stream>>>(bufA, (const unsigned int*)hb,
                                                        rowPtr, srcList, dinvp,
                                                        b3, b3, b3, bufB, n);
    // ---- MLP head ----
    gemm_nk<<<gemmBlocks, 256, 0, stream>>>(bufB, Wp1, bp1, dinvp, bufA, nullptr, n, 1);
    nhead_f32<<<nodeBlocks, 256, 0, stream>>>(bufA, Wp2, bp2, out, n);
}

// Round 5
// 468.152 us; speedup vs baseline: 1.2171x; 1.0058x over previous
//
#include <hip/hip_runtime.h>
#include <hip/hip_bf16.h>

#define EPS_LN 1e-5f
#define NB    256             // edge chunks for hist/scatter
#define SEGCAP 16384          // srcList segment capacity per bucket (64KB LDS)

typedef int ivec4 __attribute__((ext_vector_type(4)));

// ===========================================================================
// R25: two changes on top of R24's atomic-free CSR build.
// 1) gemm_nk rewrite: 64x128 tile (782 blocks = 3.05/CU vs 1.53), k-major As
//    so the A fragment is ONE float4 ds_read (was 8 scalar b32), Ws columns
//    swizzled col'=c+4*(c>>5) to kill the 4-way bank conflict on the W
//    fragment reads. Inner loop: 3x ds_read_b128 + 32 FMA per kk (FMA-bound).
// 2) agg_post: 128-thread blocks (2 waves). One node per wave + Poisson(32)
//    degrees meant a 256-thread block retired at E[max of 4] ~= 45 edges vs
//    mean 32 (~29% waste). 2-wave blocks cut straggler waste to ~10%.
// ===========================================================================

__global__ __launch_bounds__(256) void bucket_hist(const int* __restrict__ col,
                                                   int* __restrict__ chunkBH,
                                                   int E, int per, int nbuck) {
    __shared__ int hist[256];
    int t = threadIdx.x;
    hist[t] = 0;
    __syncthreads();
    int s0 = blockIdx.x * per;
    int s1 = s0 + per; if (s1 > E) s1 = E;
    if (s0 < s1) {
        int q0 = s0 >> 2, q1 = s1 >> 2;
        for (int i = q0 + t; i < q1; i += 256) {
            ivec4 c = __builtin_nontemporal_load((const ivec4*)col + i);
            atomicAdd(&hist[c.x >> 8], 1);
            atomicAdd(&hist[c.y >> 8], 1);
            atomicAdd(&hist[c.z >> 8], 1);
            atomicAdd(&hist[c.w >> 8], 1);
        }
        for (int i = (q1 << 2) + t; i < s1; i += 256)
            atomicAdd(&hist[col[i] >> 8], 1);
    }
    __syncthreads();
    if (t < nbuck) chunkBH[blockIdx.x * 256 + t] = hist[t];   // [k][b], coalesced
}

__global__ __launch_bounds__(256) void bucket_scan(int* __restrict__ chunkBH,
                                                   int* __restrict__ bucketStart,
                                                   int* __restrict__ rowPtr,
                                                   int E, int n, int nbuck, int nb) {
    __shared__ int tot[256];
    int t = threadIdx.x;
    int run = 0;
    if (t < nbuck) {
        for (int k0 = 0; k0 < nb; k0 += 16) {
            int v[16];
#pragma unroll
            for (int j = 0; j < 16; j++)
                v[j] = (k0 + j < nb) ? chunkBH[(k0 + j) * 256 + t] : 0;
#pragma unroll
            for (int j = 0; j < 16; j++) {
                int tv = v[j];
                if (k0 + j < nb) chunkBH[(k0 + j) * 256 + t] = run;
                run += tv;
            }
        }
    }
    tot[t] = run;
    __syncthreads();
    for (int d = 1; d < 256; d <<= 1) {
        int add = (t >= d) ? tot[t - d] : 0;
        __syncthreads();
        tot[t] += add;
        __syncthreads();
    }
    if (t < nbuck) bucketStart[t] = tot[t] - run;
    if (t == 0) { bucketStart[nbuck] = E; rowPtr[n] = E; }
}

__global__ __launch_bounds__(256) void scatter_pairs(const int* __restrict__ row,
                                                     const int* __restrict__ col,
                                                     const int* __restrict__ chunkBH,
                                                     const int* __restrict__ bucketStart,
                                                     unsigned long long* __restrict__ tmp,
                                                     int E, int per, int nbuck) {
    __shared__ int curs[256];
    int t = threadIdx.x;
    int k = blockIdx.x;
    curs[t] = (t < nbuck) ? (chunkBH[k * 256 + t] + bucketStart[t]) : 0;
    __syncthreads();
    int s0 = k * per;
    int s1 = s0 + per; if (s1 > E) s1 = E;
    if (s0 >= s1) return;
    int q0 = s0 >> 2, q1 = s1 >> 2;
    for (int i = q0 + t; i < q1; i += 256) {
        ivec4 c4 = __builtin_nontemporal_load((const ivec4*)col + i);
        ivec4 r4 = __builtin_nontemporal_load((const ivec4*)row + i);
        int p0 = atomicAdd(&curs[c4.x >> 8], 1);
        tmp[p0] = ((unsigned long long)(unsigned)c4.x << 32) | (unsigned)r4.x;
        int p1 = atomicAdd(&curs[c4.y >> 8], 1);
        tmp[p1] = ((unsigned long long)(unsigned)c4.y << 32) | (unsigned)r4.y;
        int p2 = atomicAdd(&curs[c4.z >> 8], 1);
        tmp[p2] = ((unsigned long long)(unsigned)c4.z << 32) | (unsigned)r4.z;
        int p3 = atomicAdd(&curs[c4.w >> 8], 1);
        tmp[p3] = ((unsigned long long)(unsigned)c4.w << 32) | (unsigned)r4.w;
    }
    for (int i = (q1 << 2) + t; i < s1; i += 256) {
        int c = col[i], r = row[i];
        int p = atomicAdd(&curs[c >> 8], 1);
        tmp[p] = ((unsigned long long)(unsigned)c << 32) | (unsigned)r;
    }
}

__global__ __launch_bounds__(256) void bucket_fill(const unsigned long long* __restrict__ tmp,
                                                   const int* __restrict__ bucketStart,
                                                   int* __restrict__ rowPtr,
                                                   float* __restrict__ dinv,
                                                   int* __restrict__ srcList,
                                                   int n) {
    __shared__ int cnt[256];
    __shared__ int cur[256];
    __shared__ int seg[SEGCAP];
    int b = blockIdx.x, t = threadIdx.x;
    int node0 = b << 8;
    int s0 = bucketStart[b], s1 = bucketStart[b + 1];
    int len = s1 - s0;
    cnt[t] = 0;
    __syncthreads();
    for (int i = s0 + t; i < s1; i += 256) {
        int c = (int)(tmp[i] >> 32);
        atomicAdd(&cnt[c - node0], 1);
    }
    __syncthreads();
    int v = cnt[t];
    cur[t] = v;
    __syncthreads();
    for (int d = 1; d < 256; d <<= 1) {
        int add = (t >= d) ? cur[t - d] : 0;
        __syncthreads();
        cur[t] += add;
        __syncthreads();
    }
    int excl = cur[t] - v;
    int node = node0 + t;
    if (node < n) {
        rowPtr[node] = s0 + excl;
        dinv[node] = rsqrtf((float)v + 1.0f);   // +1 self-loop
    }
    cur[t] = excl;
    __syncthreads();
    if (len <= SEGCAP) {
        for (int i = s0 + t; i < s1; i += 256) {
            unsigned long long p = tmp[i];
            int c = (int)(p >> 32);
            int r = (int)(p & 0xffffffffu);
            int pos = atomicAdd(&cur[c - node0], 1);
            seg[pos] = r;
        }
        __syncthreads();
        for (int i = t; i < len; i += 256)
            srcList[s0 + i] = seg[i];
    } else {                                    // overflow fallback (never for this graph)
        for (int i = s0 + t; i < s1; i += 256) {
            unsigned long long p = tmp[i];
            int c = (int)(p >> 32);
            int r = (int)(p & 0xffffffffu);
            int pos = atomicAdd(&cur[c - node0], 1);
            srcList[s0 + pos] = r;
        }
    }
}

// ---------------------------------------------------------------------------
// GEMM v2: 64x128 block tile, 256 threads, 4x8 per thread, BK=16.
// As is k-major [16][68]: A fragment = one conflict-free float4 ds_read
// (4 ig-groups hit disjoint bank quads). Ws columns swizzled by
// col' = c + 4*(c>>5): W fragment reads at the free 2-way bank minimum.
// ---------------------------------------------------------------------------
__global__ __launch_bounds__(256) void gemm_nk(const float* __restrict__ A,
                                               const float* __restrict__ W,
                                               const float* __restrict__ bias,
                                               const float* __restrict__ dinv,
                                               float* __restrict__ C,
                                               unsigned short* __restrict__ Cb,
                                               int n, int addb) {
    __shared__ float As[16][68];
    __shared__ float Ws[16][144];

    const int tx = threadIdx.x;
    const int row0 = blockIdx.x * 64;
    const int jg = (tx & 15) * 8;      // output col group (8 cols)
    const int ig = (tx >> 4) * 4;      // output row group (4 rows)
    const int js = jg + ((jg >> 5) << 2);   // swizzled Ws col

    const int ar  = tx >> 2;           // 0..63 : A-stage row
    const int ac4 = (tx & 3) * 4;      // 0,4,8,12 : A-stage k base
    const int growA = row0 + ar;
    const float* Ap = A + (size_t)growA * 128 + ac4;

    float acc[4][8];
#pragma unroll
    for (int r = 0; r < 4; r++)
#pragma unroll
        for (int c = 0; c < 8; c++) acc[r][c] = 0.f;

    for (int k0 = 0; k0 < 128; k0 += 16) {
        float4 va = make_float4(0.f, 0.f, 0.f, 0.f);
        if (growA < n) va = *(const float4*)(Ap + k0);
        As[ac4 + 0][ar] = va.x;
        As[ac4 + 1][ar] = va.y;
        As[ac4 + 2][ar] = va.z;
        As[ac4 + 3][ar] = va.w;
#pragma unroll
        for (int q = 0; q < 2; q++) {
            int f = tx * 2 + q;
            int kr = f >> 5;                 // 0..15
            int c4 = (f & 31) * 4;           // 0..124
            int cs = c4 + ((c4 >> 5) << 2);  // swizzle
            *(float4*)&Ws[kr][cs] = *(const float4*)(W + (size_t)(k0 + kr) * 128 + c4);
        }
        __syncthreads();
#pragma unroll
        for (int kk = 0; kk < 16; kk++) {
            float4 a4 = *(const float4*)&As[kk][ig];
            float4 w0 = *(const float4*)&Ws[kk][js];
            float4 w1 = *(const float4*)&Ws[kk][js + 4];
            float av[4] = {a4.x, a4.y, a4.z, a4.w};
            float wv[8] = {w0.x, w0.y, w0.z, w0.w, w1.x, w1.y, w1.z, w1.w};
#pragma unroll
            for (int r = 0; r < 4; r++)
#pragma unroll
                for (int c = 0; c < 8; c++) acc[r][c] += av[r] * wv[c];
        }
        __syncthreads();
    }

    float bv[8] = {0.f, 0.f, 0.f, 0.f, 0.f, 0.f, 0.f, 0.f};
    if (addb) {
        float4 b0 = *(const float4*)(bias + jg);
        float4 b1 = *(const float4*)(bias + jg + 4);
        bv[0] = b0.x; bv[1] = b0.y; bv[2] = b0.z; bv[3] = b0.w;
        bv[4] = b1.x; bv[5] = b1.y; bv[6] = b1.z; bv[7] = b1.w;
    }
#pragma unroll
    for (int r = 0; r < 4; r++) {
        int grow = row0 + ig + r;
        if (grow < n) {
            float o[8];
#pragma unroll
            for (int c = 0; c < 8; c++) o[c] = acc[r][c] + bv[c];
            *(float4*)(C + (size_t)grow * 128 + jg)     = make_float4(o[0], o[1], o[2], o[3]);
            *(float4*)(C + (size_t)grow * 128 + jg + 4) = make_float4(o[4], o[5], o[6], o[7]);
            if (Cb) {
                float dr = dinv[grow];
                ushort4 u0, u1;
                __hip_bfloat16 t;
                t = __float2bfloat16(o[0] * dr); u0.x = *(unsigned short*)&t;
                t = __float2bfloat16(o[1] * dr); u0.y = *(unsigned short*)&t;
                t = __float2bfloat16(o[2] * dr); u0.z = *(unsigned short*)&t;
                t = __float2bfloat16(o[3] * dr); u0.w = *(unsigned short*)&t;
                t = __float2bfloat16(o[4] * dr); u1.x = *(unsigned short*)&t;
                t = __float2bfloat16(o[5] * dr); u1.y = *(unsigned short*)&t;
                t = __float2bfloat16(o[6] * dr); u1.z = *(unsigned short*)&t;
                t = __float2bfloat16(o[7] * dr); u1.w = *(unsigned short*)&t;
                *(ushort4*)(Cb + (size_t)grow * 128 + jg)     = u0;
                *(ushort4*)(Cb + (size_t)grow * 128 + jg + 4) = u1;
            }
        }
    }
}

// ---------------------------------------------------------------------------
// Fused gather (bf16 pre-scaled) + self-loop(f32) + bias + relu (+ LN).
// 128-thread blocks (2 waves): Poisson-degree straggler waste ~10% vs ~29%.
// ---------------------------------------------------------------------------
template<bool DO_LN>
__global__ __launch_bounds__(128) void agg_post(const float* __restrict__ h,
                                                const unsigned int* __restrict__ hb,
                                                const int* __restrict__ rowPtr,
                                                const int* __restrict__ srcList,
                                                const float* __restrict__ dinv,
                                                const float* __restrict__ b,
                                                const float* __restrict__ g,
                                                const float* __restrict__ beta,
                                                float* __restrict__ out, int n) {
    int wid = (blockIdx.x * 128 + threadIdx.x) >> 6;
    int lane = threadIdx.x & 63;
    if (wid >= n) return;
    int e0 = rowPtr[wid], e1 = rowPtr[wid + 1];
    float dc = dinv[wid];
    size_t base = (size_t)wid * 128 + lane * 2;
    float2 hs = *(const float2*)(h + base);
    float ax = hs.x * dc * dc;
    float ay = hs.y * dc * dc;

    int e = e0;
    for (; e + 8 <= e1; e += 8) {
        int r0 = srcList[e + 0], r1 = srcList[e + 1];
        int r2 = srcList[e + 2], r3 = srcList[e + 3];
        int r4 = srcList[e + 4], r5 = srcList[e + 5];
        int r6 = srcList[e + 6], r7 = srcList[e + 7];
        unsigned int u0 = hb[(size_t)r0 * 64 + lane];
        unsigned int u1 = hb[(size_t)r1 * 64 + lane];
        unsigned int u2 = hb[(size_t)r2 * 64 + lane];
        unsigned int u3 = hb[(size_t)r3 * 64 + lane];
        unsigned int u4 = hb[(size_t)r4 * 64 + lane];
        unsigned int u5 = hb[(size_t)r5 * 64 + lane];
        unsigned int u6 = hb[(size_t)r6 * 64 + lane];
        unsigned int u7 = hb[(size_t)r7 * 64 + lane];
        ax += __uint_as_float(u0 << 16) * dc;  ay += __uint_as_float(u0 & 0xffff0000u) * dc;
        ax += __uint_as_float(u1 << 16) * dc;  ay += __uint_as_float(u1 & 0xffff0000u) * dc;
        ax += __uint_as_float(u2 << 16) * dc;  ay += __uint_as_float(u2 & 0xffff0000u) * dc;
        ax += __uint_as_float(u3 << 16) * dc;  ay += __uint_as_float(u3 & 0xffff0000u) * dc;
        ax += __uint_as_float(u4 << 16) * dc;  ay += __uint_as_float(u4 & 0xffff0000u) * dc;
        ax += __uint_as_float(u5 << 16) * dc;  ay += __uint_as_float(u5 & 0xffff0000u) * dc;
        ax += __uint_as_float(u6 << 16) * dc;  ay += __uint_as_float(u6 & 0xffff0000u) * dc;
        ax += __uint_as_float(u7 << 16) * dc;  ay += __uint_as_float(u7 & 0xffff0000u) * dc;
    }
    for (; e < e1; e++) {
        int r = srcList[e];
        unsigned int u = hb[(size_t)r * 64 + lane];
        ax += __uint_as_float(u << 16) * dc;
        ay += __uint_as_float(u & 0xffff0000u) * dc;
    }

    ax = fmaxf(ax + b[lane * 2 + 0], 0.f);
    ay = fmaxf(ay + b[lane * 2 + 1], 0.f);
    if (DO_LN) {
        float s = ax + ay;
#pragma unroll
        for (int m = 32; m >= 1; m >>= 1) s += __shfl_xor(s, m, 64);
        float mu = s * (1.f / 128.f);
        float dx = ax - mu, dy = ay - mu;
        float sq = dx * dx + dy * dy;
#pragma unroll
        for (int m = 32; m >= 1; m >>= 1) sq += __shfl_xor(sq, m, 64);
        float rs = rsqrtf(sq * (1.f / 128.f) + EPS_LN);
        ax = dx * rs * g[lane * 2 + 0] + beta[lane * 2 + 0];
        ay = dy * rs * g[lane * 2 + 1] + beta[lane * 2 + 1];
    }
    *(float2*)(out + base) = make_float2(ax, ay);
}

// ---------------------------------------------------------------------------
__global__ __launch_bounds__(256) void nhead_f32(const float* __restrict__ hp,
                                                 const float* __restrict__ W,
                                                 const float* __restrict__ b,
                                                 float* __restrict__ out, int n) {
    __shared__ float Ws[384];
    int t = threadIdx.x;
    if (t < 192) { Ws[t] = W[t]; Ws[t + 192] = W[t + 192]; }
    __syncthreads();
    int i = blockIdx.x * 256 + t;
    if (i >= n) return;
    float p0 = b[0], p1 = b[1], p2 = b[2];
    const float4* h4 = (const float4*)(hp + (size_t)i * 128);
#pragma unroll
    for (int k4 = 0; k4 < 32; k4++) {
        float4 v = h4[k4];
        const float* w = &Ws[k4 * 12];
        p0 += v.x * w[0] + v.y * w[3] + v.z * w[6] + v.w * w[9];
        p1 += v.x * w[1] + v.y * w[4] + v.z * w[7] + v.w * w[10];
        p2 += v.x * w[2] + v.y * w[5] + v.z * w[8] + v.w * w[11];
    }
    out[(size_t)i * 3 + 0] = p0;
    out[(size_t)i * 3 + 1] = p1;
    out[(size_t)i * 3 + 2] = p2;
}

// ---------------------------------------------------------------------------
extern "C" void kernel_launch(void* const* d_in, const int* in_sizes, int n_in,
                              void* d_out, int out_size, void* d_ws, size_t ws_size,
                              hipStream_t stream) {
    const float* x   = (const float*)d_in[0];
    const int* ei    = (const int*)d_in[1];
    const float* W1  = (const float*)d_in[2];
    const float* b1  = (const float*)d_in[3];
    const float* W2  = (const float*)d_in[4];
    const float* b2  = (const float*)d_in[5];
    const float* W3  = (const float*)d_in[6];
    const float* b3  = (const float*)d_in[7];
    const float* g1  = (const float*)d_in[8];
    const float* be1 = (const float*)d_in[9];
    const float* g2  = (const float*)d_in[10];
    const float* be2 = (const float*)d_in[11];
    const float* Wp1 = (const float*)d_in[12];
    const float* bp1 = (const float*)d_in[13];
    const float* Wp2 = (const float*)d_in[14];
    const float* bp2 = (const float*)d_in[15];
    float* out = (float*)d_out;

    const int n = in_sizes[0] / 128;   // 50000
    const int E = in_sizes[1] / 2;     // 1600000
    const int* row = ei;
    const int* col = ei + E;

    char* ws = (char*)d_ws;
    size_t nA  = ((size_t)n * 4 + 255) & ~(size_t)255;
    size_t nA1 = ((size_t)(n + 1) * 4 + 255) & ~(size_t)255;
    size_t eA  = ((size_t)E * 4 + 255) & ~(size_t)255;
    size_t hbA = ((size_t)n * 128 * 2 + 255) & ~(size_t)255;
    int*   rowPtr  = (int*)ws;
    float* dinvp   = (float*)(ws + nA1);
    int*   srcList = (int*)(ws + nA1 + nA);
    unsigned short* hb = (unsigned short*)(ws + nA1 + nA + eA);
    float* bufA    = (float*)(ws + nA1 + nA + eA + hbA);
    float* bufB    = bufA + (size_t)n * 128;
    // CSR scratch aliases bufA (25.6MB; consumed before layer-1 gemm):
    //   tmp pairs 12.8MB, chunkBH 256KB, bucketStart ~1KB
    unsigned long long* tmp = (unsigned long long*)bufA;
    int* chunkBH    = (int*)((char*)bufA + 2 * eA);
    int* bucketStart = (int*)((char*)bufA + 2 * eA + (size_t)NB * 256 * 4);

    const int nbuck = (n + 255) >> 8;                 // 196
    const int per   = (((E + NB - 1) / NB) + 15) & ~15;  // 16-aligned chunk size
    const int gemmBlocks = (n + 63) / 64;             // 782
    const int nodeWaveBlocks = (n + 1) / 2;           // 2 waves/block
    const int nodeBlocks = (n + 255) / 256;

    // CSR build (bucketed counting sort, zero global atomics)
    bucket_hist<<<NB, 256, 0, stream>>>(col, chunkBH, E, per, nbuck);
    bucket_scan<<<1, 256, 0, stream>>>(chunkBH, bucketStart, rowPtr, E, n, nbuck, NB);
    scatter_pairs<<<NB, 256, 0, stream>>>(row, col, chunkBH, bucketStart, tmp, E, per, nbuck);
    bucket_fill<<<nbuck, 256, 0, stream>>>(tmp, bucketStart, rowPtr, dinvp, srcList, n);

    // ---- layer 1 ----
    gemm_nk<<<gemmBlocks, 256, 0, stream>>>(x, W1, b1, dinvp, bufA, hb, n, 0);
    agg_post<true><<<nodeWaveBlocks, 128, 0, stream>>>(bufA, (const unsigned int*)hb,
                                                       rowPtr, srcList, dinvp,
                                                       b1, g1, be1, bufB, n);
    // ---- layer 2 ----
    gemm_nk<<<gemmBlocks, 256, 0, stream>>>(bufB, W2, b2, dinvp, bufA, hb, n, 0);
    agg_post<true><<<nodeWaveBlocks, 128, 0, stream>>>(bufA, (const unsigned int*)hb,
                                                       rowPtr, srcList, dinvp,
                                                       b2, g2, be2, bufB, n);
    // ---- layer 3 (relu, no LN) ----
    gemm_nk<<<gemmBlocks, 256, 0, stream>>>(bufB, W3, b3, dinvp, bufA, hb, n, 0);
    agg_post<false><<<nodeWaveBlocks, 128, 0, stream>>>(bufA, (const unsigned int*)hb,
                                                        rowPtr, srcList, dinvp,
                                                        b3, b3, b3, bufB, n);
    // ---- MLP head ----
    gemm_nk<<<gemmBlocks, 256, 0, stream>>>(bufB, Wp1, bp1, dinvp, bufA, nullptr, n, 1);
    nhead_f32<<<nodeBlocks, 256, 0, stream>>>(bufA, Wp2, bp2, out, n);
}

// Round 6
// 431.152 us; speedup vs baseline: 1.3215x; 1.0858x over previous
//
#include <hip/hip_runtime.h>
#include <hip/hip_bf16.h>

#define EPS_LN 1e-5f
#define NB    256             // edge chunks for hist/scatter
#define SEGCAP 16384          // srcList segment capacity per bucket (64KB LDS)

typedef int ivec4 __attribute__((ext_vector_type(4)));

// ===========================================================================
// R26: two changes on top of R25.
// 1) agg_post v3: wave split into even/odd edge halves; each lane loads uint2
//    (8B = 4 bf16 features) so ONE wave-load covers 2 edges (512B/instr vs
//    256B). Gather instruction count halves; 4 loads in flight. Cross-half
//    shfl_xor(32) merges partials; dc applied once.
// 2) Head collapse: Wp1@Wp2 has no nonlinearity between -> precompute
//    Weff[128][3], beff[3] on device (head_collapse, ~3us) and delete the
//    4th GEMM (25.6MB write + 25.6MB read).
// ===========================================================================

__global__ __launch_bounds__(256) void bucket_hist(const int* __restrict__ col,
                                                   int* __restrict__ chunkBH,
                                                   int E, int per, int nbuck) {
    __shared__ int hist[256];
    int t = threadIdx.x;
    hist[t] = 0;
    __syncthreads();
    int s0 = blockIdx.x * per;
    int s1 = s0 + per; if (s1 > E) s1 = E;
    if (s0 < s1) {
        int q0 = s0 >> 2, q1 = s1 >> 2;
        for (int i = q0 + t; i < q1; i += 256) {
            ivec4 c = __builtin_nontemporal_load((const ivec4*)col + i);
            atomicAdd(&hist[c.x >> 8], 1);
            atomicAdd(&hist[c.y >> 8], 1);
            atomicAdd(&hist[c.z >> 8], 1);
            atomicAdd(&hist[c.w >> 8], 1);
        }
        for (int i = (q1 << 2) + t; i < s1; i += 256)
            atomicAdd(&hist[col[i] >> 8], 1);
    }
    __syncthreads();
    if (t < nbuck) chunkBH[blockIdx.x * 256 + t] = hist[t];   // [k][b], coalesced
}

__global__ __launch_bounds__(256) void bucket_scan(int* __restrict__ chunkBH,
                                                   int* __restrict__ bucketStart,
                                                   int* __restrict__ rowPtr,
                                                   int E, int n, int nbuck, int nb) {
    __shared__ int tot[256];
    int t = threadIdx.x;
    int run = 0;
    if (t < nbuck) {
        for (int k0 = 0; k0 < nb; k0 += 16) {
            int v[16];
#pragma unroll
            for (int j = 0; j < 16; j++)
                v[j] = (k0 + j < nb) ? chunkBH[(k0 + j) * 256 + t] : 0;
#pragma unroll
            for (int j = 0; j < 16; j++) {
                int tv = v[j];
                if (k0 + j < nb) chunkBH[(k0 + j) * 256 + t] = run;
                run += tv;
            }
        }
    }
    tot[t] = run;
    __syncthreads();
    for (int d = 1; d < 256; d <<= 1) {
        int add = (t >= d) ? tot[t - d] : 0;
        __syncthreads();
        tot[t] += add;
        __syncthreads();
    }
    if (t < nbuck) bucketStart[t] = tot[t] - run;
    if (t == 0) { bucketStart[nbuck] = E; rowPtr[n] = E; }
}

__global__ __launch_bounds__(256) void scatter_pairs(const int* __restrict__ row,
                                                     const int* __restrict__ col,
                                                     const int* __restrict__ chunkBH,
                                                     const int* __restrict__ bucketStart,
                                                     unsigned long long* __restrict__ tmp,
                                                     int E, int per, int nbuck) {
    __shared__ int curs[256];
    int t = threadIdx.x;
    int k = blockIdx.x;
    curs[t] = (t < nbuck) ? (chunkBH[k * 256 + t] + bucketStart[t]) : 0;
    __syncthreads();
    int s0 = k * per;
    int s1 = s0 + per; if (s1 > E) s1 = E;
    if (s0 >= s1) return;
    int q0 = s0 >> 2, q1 = s1 >> 2;
    for (int i = q0 + t; i < q1; i += 256) {
        ivec4 c4 = __builtin_nontemporal_load((const ivec4*)col + i);
        ivec4 r4 = __builtin_nontemporal_load((const ivec4*)row + i);
        int p0 = atomicAdd(&curs[c4.x >> 8], 1);
        tmp[p0] = ((unsigned long long)(unsigned)c4.x << 32) | (unsigned)r4.x;
        int p1 = atomicAdd(&curs[c4.y >> 8], 1);
        tmp[p1] = ((unsigned long long)(unsigned)c4.y << 32) | (unsigned)r4.y;
        int p2 = atomicAdd(&curs[c4.z >> 8], 1);
        tmp[p2] = ((unsigned long long)(unsigned)c4.z << 32) | (unsigned)r4.z;
        int p3 = atomicAdd(&curs[c4.w >> 8], 1);
        tmp[p3] = ((unsigned long long)(unsigned)c4.w << 32) | (unsigned)r4.w;
    }
    for (int i = (q1 << 2) + t; i < s1; i += 256) {
        int c = col[i], r = row[i];
        int p = atomicAdd(&curs[c >> 8], 1);
        tmp[p] = ((unsigned long long)(unsigned)c << 32) | (unsigned)r;
    }
}

__global__ __launch_bounds__(256) void bucket_fill(const unsigned long long* __restrict__ tmp,
                                                   const int* __restrict__ bucketStart,
                                                   int* __restrict__ rowPtr,
                                                   float* __restrict__ dinv,
                                                   int* __restrict__ srcList,
                                                   int n) {
    __shared__ int cnt[256];
    __shared__ int cur[256];
    __shared__ int seg[SEGCAP];
    int b = blockIdx.x, t = threadIdx.x;
    int node0 = b << 8;
    int s0 = bucketStart[b], s1 = bucketStart[b + 1];
    int len = s1 - s0;
    cnt[t] = 0;
    __syncthreads();
    for (int i = s0 + t; i < s1; i += 256) {
        int c = (int)(tmp[i] >> 32);
        atomicAdd(&cnt[c - node0], 1);
    }
    __syncthreads();
    int v = cnt[t];
    cur[t] = v;
    __syncthreads();
    for (int d = 1; d < 256; d <<= 1) {
        int add = (t >= d) ? cur[t - d] : 0;
        __syncthreads();
        cur[t] += add;
        __syncthreads();
    }
    int excl = cur[t] - v;
    int node = node0 + t;
    if (node < n) {
        rowPtr[node] = s0 + excl;
        dinv[node] = rsqrtf((float)v + 1.0f);   // +1 self-loop
    }
    cur[t] = excl;
    __syncthreads();
    if (len <= SEGCAP) {
        for (int i = s0 + t; i < s1; i += 256) {
            unsigned long long p = tmp[i];
            int c = (int)(p >> 32);
            int r = (int)(p & 0xffffffffu);
            int pos = atomicAdd(&cur[c - node0], 1);
            seg[pos] = r;
        }
        __syncthreads();
        for (int i = t; i < len; i += 256)
            srcList[s0 + i] = seg[i];
    } else {                                    // overflow fallback (never for this graph)
        for (int i = s0 + t; i < s1; i += 256) {
            unsigned long long p = tmp[i];
            int c = (int)(p >> 32);
            int r = (int)(p & 0xffffffffu);
            int pos = atomicAdd(&cur[c - node0], 1);
            srcList[s0 + pos] = r;
        }
    }
}

// ---------------------------------------------------------------------------
// GEMM v2: 64x128 block tile, 256 threads, 4x8 per thread, BK=16 (R25).
// ---------------------------------------------------------------------------
__global__ __launch_bounds__(256) void gemm_nk(const float* __restrict__ A,
                                               const float* __restrict__ W,
                                               const float* __restrict__ bias,
                                               const float* __restrict__ dinv,
                                               float* __restrict__ C,
                                               unsigned short* __restrict__ Cb,
                                               int n, int addb) {
    __shared__ float As[16][68];
    __shared__ float Ws[16][144];

    const int tx = threadIdx.x;
    const int row0 = blockIdx.x * 64;
    const int jg = (tx & 15) * 8;      // output col group (8 cols)
    const int ig = (tx >> 4) * 4;      // output row group (4 rows)
    const int js = jg + ((jg >> 5) << 2);   // swizzled Ws col

    const int ar  = tx >> 2;           // 0..63 : A-stage row
    const int ac4 = (tx & 3) * 4;      // 0,4,8,12 : A-stage k base
    const int growA = row0 + ar;
    const float* Ap = A + (size_t)growA * 128 + ac4;

    float acc[4][8];
#pragma unroll
    for (int r = 0; r < 4; r++)
#pragma unroll
        for (int c = 0; c < 8; c++) acc[r][c] = 0.f;

    for (int k0 = 0; k0 < 128; k0 += 16) {
        float4 va = make_float4(0.f, 0.f, 0.f, 0.f);
        if (growA < n) va = *(const float4*)(Ap + k0);
        As[ac4 + 0][ar] = va.x;
        As[ac4 + 1][ar] = va.y;
        As[ac4 + 2][ar] = va.z;
        As[ac4 + 3][ar] = va.w;
#pragma unroll
        for (int q = 0; q < 2; q++) {
            int f = tx * 2 + q;
            int kr = f >> 5;                 // 0..15
            int c4 = (f & 31) * 4;           // 0..124
            int cs = c4 + ((c4 >> 5) << 2);  // swizzle
            *(float4*)&Ws[kr][cs] = *(const float4*)(W + (size_t)(k0 + kr) * 128 + c4);
        }
        __syncthreads();
#pragma unroll
        for (int kk = 0; kk < 16; kk++) {
            float4 a4 = *(const float4*)&As[kk][ig];
            float4 w0 = *(const float4*)&Ws[kk][js];
            float4 w1 = *(const float4*)&Ws[kk][js + 4];
            float av[4] = {a4.x, a4.y, a4.z, a4.w};
            float wv[8] = {w0.x, w0.y, w0.z, w0.w, w1.x, w1.y, w1.z, w1.w};
#pragma unroll
            for (int r = 0; r < 4; r++)
#pragma unroll
                for (int c = 0; c < 8; c++) acc[r][c] += av[r] * wv[c];
        }
        __syncthreads();
    }

    float bv[8] = {0.f, 0.f, 0.f, 0.f, 0.f, 0.f, 0.f, 0.f};
    if (addb) {
        float4 b0 = *(const float4*)(bias + jg);
        float4 b1 = *(const float4*)(bias + jg + 4);
        bv[0] = b0.x; bv[1] = b0.y; bv[2] = b0.z; bv[3] = b0.w;
        bv[4] = b1.x; bv[5] = b1.y; bv[6] = b1.z; bv[7] = b1.w;
    }
#pragma unroll
    for (int r = 0; r < 4; r++) {
        int grow = row0 + ig + r;
        if (grow < n) {
            float o[8];
#pragma unroll
            for (int c = 0; c < 8; c++) o[c] = acc[r][c] + bv[c];
            *(float4*)(C + (size_t)grow * 128 + jg)     = make_float4(o[0], o[1], o[2], o[3]);
            *(float4*)(C + (size_t)grow * 128 + jg + 4) = make_float4(o[4], o[5], o[6], o[7]);
            if (Cb) {
                float dr = dinv[grow];
                ushort4 u0, u1;
                __hip_bfloat16 t;
                t = __float2bfloat16(o[0] * dr); u0.x = *(unsigned short*)&t;
                t = __float2bfloat16(o[1] * dr); u0.y = *(unsigned short*)&t;
                t = __float2bfloat16(o[2] * dr); u0.z = *(unsigned short*)&t;
                t = __float2bfloat16(o[3] * dr); u0.w = *(unsigned short*)&t;
                t = __float2bfloat16(o[4] * dr); u1.x = *(unsigned short*)&t;
                t = __float2bfloat16(o[5] * dr); u1.y = *(unsigned short*)&t;
                t = __float2bfloat16(o[6] * dr); u1.z = *(unsigned short*)&t;
                t = __float2bfloat16(o[7] * dr); u1.w = *(unsigned short*)&t;
                *(ushort4*)(Cb + (size_t)grow * 128 + jg)     = u0;
                *(ushort4*)(Cb + (size_t)grow * 128 + jg + 4) = u1;
            }
        }
    }
}

// ---------------------------------------------------------------------------
// agg_post v3: wave = 1 node; lanes 0-31 even edges, 32-63 odd edges.
// Each lane owns features 4h..4h+3 (h = lane&31) and loads uint2 (8B).
// One wave-load covers 2 edges (512B). Cross-half shfl_xor(32) merges.
// ---------------------------------------------------------------------------
#define BF_LO(u) __uint_as_float((u) << 16)
#define BF_HI(u) __uint_as_float((u) & 0xffff0000u)

template<bool DO_LN>
__global__ __launch_bounds__(128) void agg_post(const float* __restrict__ h,
                                                const unsigned int* __restrict__ hb,
                                                const int* __restrict__ rowPtr,
                                                const int* __restrict__ srcList,
                                                const float* __restrict__ dinv,
                                                const float* __restrict__ b,
                                                const float* __restrict__ g,
                                                const float* __restrict__ beta,
                                                float* __restrict__ out, int n) {
    int wid = (blockIdx.x * 128 + threadIdx.x) >> 6;
    int lane = threadIdx.x & 63;
    if (wid >= n) return;
    int hq = lane & 31;        // feature-quad index: features 4hq..4hq+3
    int half = lane >> 5;      // 0: even edges, 1: odd edges
    int e0 = rowPtr[wid], e1 = rowPtr[wid + 1];
    float dc = dinv[wid];
    const uint2* hb2 = (const uint2*)hb;   // 32 uint2 per 128-feature row

    float a0 = 0.f, a1 = 0.f, a2 = 0.f, a3 = 0.f;
    int e = e0;
    for (; e + 8 <= e1; e += 8) {
        int r0 = srcList[e + 0 + half];
        int r1 = srcList[e + 2 + half];
        int r2 = srcList[e + 4 + half];
        int r3 = srcList[e + 6 + half];
        uint2 u0 = hb2[(size_t)r0 * 32 + hq];
        uint2 u1 = hb2[(size_t)r1 * 32 + hq];
        uint2 u2 = hb2[(size_t)r2 * 32 + hq];
        uint2 u3 = hb2[(size_t)r3 * 32 + hq];
        a0 += BF_LO(u0.x); a1 += BF_HI(u0.x); a2 += BF_LO(u0.y); a3 += BF_HI(u0.y);
        a0 += BF_LO(u1.x); a1 += BF_HI(u1.x); a2 += BF_LO(u1.y); a3 += BF_HI(u1.y);
        a0 += BF_LO(u2.x); a1 += BF_HI(u2.x); a2 += BF_LO(u2.y); a3 += BF_HI(u2.y);
        a0 += BF_LO(u3.x); a1 += BF_HI(u3.x); a2 += BF_LO(u3.y); a3 += BF_HI(u3.y);
    }
    for (; e + 2 <= e1; e += 2) {
        int r = srcList[e + half];
        uint2 u = hb2[(size_t)r * 32 + hq];
        a0 += BF_LO(u.x); a1 += BF_HI(u.x); a2 += BF_LO(u.y); a3 += BF_HI(u.y);
    }
    if (e < e1 && half == 0) {     // odd-degree leftover: half 0 only
        int r = srcList[e];
        uint2 u = hb2[(size_t)r * 32 + hq];
        a0 += BF_LO(u.x); a1 += BF_HI(u.x); a2 += BF_LO(u.y); a3 += BF_HI(u.y);
    }
    // merge even/odd halves
    a0 += __shfl_xor(a0, 32, 64);
    a1 += __shfl_xor(a1, 32, 64);
    a2 += __shfl_xor(a2, 32, 64);
    a3 += __shfl_xor(a3, 32, 64);

    // scale + self-loop + bias + relu
    float4 hs = *(const float4*)(h + (size_t)wid * 128 + hq * 4);
    float4 bv = *(const float4*)(b + hq * 4);
    a0 = fmaxf(a0 * dc + hs.x * dc * dc + bv.x, 0.f);
    a1 = fmaxf(a1 * dc + hs.y * dc * dc + bv.y, 0.f);
    a2 = fmaxf(a2 * dc + hs.z * dc * dc + bv.z, 0.f);
    a3 = fmaxf(a3 * dc + hs.w * dc * dc + bv.w, 0.f);

    if (DO_LN) {
        float s = a0 + a1 + a2 + a3;
#pragma unroll
        for (int m = 16; m >= 1; m >>= 1) s += __shfl_xor(s, m, 64);
        float mu = s * (1.f / 128.f);
        float d0 = a0 - mu, d1 = a1 - mu, d2 = a2 - mu, d3 = a3 - mu;
        float sq = d0 * d0 + d1 * d1 + d2 * d2 + d3 * d3;
#pragma unroll
        for (int m = 16; m >= 1; m >>= 1) sq += __shfl_xor(sq, m, 64);
        float rs = rsqrtf(sq * (1.f / 128.f) + EPS_LN);
        float4 gv = *(const float4*)(g + hq * 4);
        float4 bt = *(const float4*)(beta + hq * 4);
        a0 = d0 * rs * gv.x + bt.x;
        a1 = d1 * rs * gv.y + bt.y;
        a2 = d2 * rs * gv.z + bt.z;
        a3 = d3 * rs * gv.w + bt.w;
    }
    if (half == 0)
        *(float4*)(out + (size_t)wid * 128 + hq * 4) = make_float4(a0, a1, a2, a3);
}

// ---------------------------------------------------------------------------
// Head collapse: Weff = Wp1 @ Wp2 (128x3), beff = bp1 @ Wp2 + bp2.
// ---------------------------------------------------------------------------
__global__ __launch_bounds__(128) void head_collapse(const float* __restrict__ Wp1,
                                                     const float* __restrict__ bp1,
                                                     const float* __restrict__ Wp2,
                                                     const float* __restrict__ bp2,
                                                     float* __restrict__ Weff,
                                                     float* __restrict__ beff) {
    __shared__ float w2[384];
    int t = threadIdx.x;
    w2[t] = Wp2[t]; w2[t + 128] = Wp2[t + 128]; w2[t + 256] = Wp2[t + 256];
    __syncthreads();
    float p0 = 0.f, p1 = 0.f, p2 = 0.f;
    const float* wr = Wp1 + (size_t)t * 128;
    for (int k = 0; k < 128; k++) {
        float v = wr[k];
        p0 += v * w2[k * 3 + 0];
        p1 += v * w2[k * 3 + 1];
        p2 += v * w2[k * 3 + 2];
    }
    Weff[t * 3 + 0] = p0; Weff[t * 3 + 1] = p1; Weff[t * 3 + 2] = p2;
    if (t == 0) {
        float q0 = bp2[0], q1 = bp2[1], q2 = bp2[2];
        for (int k = 0; k < 128; k++) {
            float v = bp1[k];
            q0 += v * w2[k * 3 + 0];
            q1 += v * w2[k * 3 + 1];
            q2 += v * w2[k * 3 + 2];
        }
        beff[0] = q0; beff[1] = q1; beff[2] = q2;
    }
}

// ---------------------------------------------------------------------------
__global__ __launch_bounds__(256) void nhead_f32(const float* __restrict__ hp,
                                                 const float* __restrict__ W,
                                                 const float* __restrict__ b,
                                                 float* __restrict__ out, int n) {
    __shared__ float Ws[384];
    int t = threadIdx.x;
    if (t < 192) { Ws[t] = W[t]; Ws[t + 192] = W[t + 192]; }
    __syncthreads();
    int i = blockIdx.x * 256 + t;
    if (i >= n) return;
    float p0 = b[0], p1 = b[1], p2 = b[2];
    const float4* h4 = (const float4*)(hp + (size_t)i * 128);
#pragma unroll
    for (int k4 = 0; k4 < 32; k4++) {
        float4 v = h4[k4];
        const float* w = &Ws[k4 * 12];
        p0 += v.x * w[0] + v.y * w[3] + v.z * w[6] + v.w * w[9];
        p1 += v.x * w[1] + v.y * w[4] + v.z * w[7] + v.w * w[10];
        p2 += v.x * w[2] + v.y * w[5] + v.z * w[8] + v.w * w[11];
    }
    out[(size_t)i * 3 + 0] = p0;
    out[(size_t)i * 3 + 1] = p1;
    out[(size_t)i * 3 + 2] = p2;
}

// ---------------------------------------------------------------------------
extern "C" void kernel_launch(void* const* d_in, const int* in_sizes, int n_in,
                              void* d_out, int out_size, void* d_ws, size_t ws_size,
                              hipStream_t stream) {
    const float* x   = (const float*)d_in[0];
    const int* ei    = (const int*)d_in[1];
    const float* W1  = (const float*)d_in[2];
    const float* b1  = (const float*)d_in[3];
    const float* W2  = (const float*)d_in[4];
    const float* b2  = (const float*)d_in[5];
    const float* W3  = (const float*)d_in[6];
    const float* b3  = (const float*)d_in[7];
    const float* g1  = (const float*)d_in[8];
    const float* be1 = (const float*)d_in[9];
    const float* g2  = (const float*)d_in[10];
    const float* be2 = (const float*)d_in[11];
    const float* Wp1 = (const float*)d_in[12];
    const float* bp1 = (const float*)d_in[13];
    const float* Wp2 = (const float*)d_in[14];
    const float* bp2 = (const float*)d_in[15];
    float* out = (float*)d_out;

    const int n = in_sizes[0] / 128;   // 50000
    const int E = in_sizes[1] / 2;     // 1600000
    const int* row = ei;
    const int* col = ei + E;

    char* ws = (char*)d_ws;
    size_t nA  = ((size_t)n * 4 + 255) & ~(size_t)255;
    size_t nA1 = ((size_t)(n + 1) * 4 + 255) & ~(size_t)255;
    size_t eA  = ((size_t)E * 4 + 255) & ~(size_t)255;
    size_t hbA = ((size_t)n * 128 * 2 + 255) & ~(size_t)255;
    int*   rowPtr  = (int*)ws;
    float* dinvp   = (float*)(ws + nA1);
    int*   srcList = (int*)(ws + nA1 + nA);
    unsigned short* hb = (unsigned short*)(ws + nA1 + nA + eA);
    float* bufA    = (float*)(ws + nA1 + nA + eA + hbA);
    float* bufB    = bufA + (size_t)n * 128;
    float* Weff    = bufB + (size_t)n * 128;     // 384 floats
    float* beff    = Weff + 384;                 // 3 floats
    // CSR scratch aliases bufA (25.6MB; consumed before layer-1 gemm):
    unsigned long long* tmp = (unsigned long long*)bufA;
    int* chunkBH    = (int*)((char*)bufA + 2 * eA);
    int* bucketStart = (int*)((char*)bufA + 2 * eA + (size_t)NB * 256 * 4);

    const int nbuck = (n + 255) >> 8;                 // 196
    const int per   = (((E + NB - 1) / NB) + 15) & ~15;  // 16-aligned chunk size
    const int gemmBlocks = (n + 63) / 64;             // 782
    const int nodeWaveBlocks = (n + 1) / 2;           // 2 waves/block
    const int nodeBlocks = (n + 255) / 256;

    // CSR build (bucketed counting sort, zero global atomics)
    bucket_hist<<<NB, 256, 0, stream>>>(col, chunkBH, E, per, nbuck);
    bucket_scan<<<1, 256, 0, stream>>>(chunkBH, bucketStart, rowPtr, E, n, nbuck, NB);
    scatter_pairs<<<NB, 256, 0, stream>>>(row, col, chunkBH, bucketStart, tmp, E, per, nbuck);
    bucket_fill<<<nbuck, 256, 0, stream>>>(tmp, bucketStart, rowPtr, dinvp, srcList, n);
    head_collapse<<<1, 128, 0, stream>>>(Wp1, bp1, Wp2, bp2, Weff, beff);

    // ---- layer 1 ----
    gemm_nk<<<gemmBlocks, 256, 0, stream>>>(x, W1, b1, dinvp, bufA, hb, n, 0);
    agg_post<true><<<nodeWaveBlocks, 128, 0, stream>>>(bufA, (const unsigned int*)hb,
                                                       rowPtr, srcList, dinvp,
                                                       b1, g1, be1, bufB, n);
    // ---- layer 2 ----
    gemm_nk<<<gemmBlocks, 256, 0, stream>>>(bufB, W2, b2, dinvp, bufA, hb, n, 0);
    agg_post<true><<<nodeWaveBlocks, 128, 0, stream>>>(bufA, (const unsigned int*)hb,
                                                       rowPtr, srcList, dinvp,
                                                       b2, g2, be2, bufB, n);
    // ---- layer 3 (relu, no LN) ----
    gemm_nk<<<gemmBlocks, 256, 0, stream>>>(bufB, W3, b3, dinvp, bufA, hb, n, 0);
    agg_post<false><<<nodeWaveBlocks, 128, 0, stream>>>(bufA, (const unsigned int*)hb,
                                                        rowPtr, srcList, dinvp,
                                                        b3, b3, b3, bufB, n);
    // ---- collapsed MLP head ----
    nhead_f32<<<nodeBlocks, 256, 0, stream>>>(bufB, Weff, beff, out, n);
}

// Round 7
// 423.637 us; speedup vs baseline: 1.3449x; 1.0177x over previous
//
#include <hip/hip_runtime.h>
#include <hip/hip_bf16.h>

#define EPS_LN 1e-5f
#define NB    256             // edge chunks for hist/scatter
#define SEGCAP 16384          // srcList segment capacity per bucket (64KB LDS)

typedef int ivec4 __attribute__((ext_vector_type(4)));

// ===========================================================================
// R27: agg_post v4. R26 post-mortem: gather loop is latency-bound on the
// srcList->gather dependent chain (~4 loads in flight), not instruction- or
// BW-bound (FETCH pinned at 166MB, hbm 40%, VALU 43%). Changes:
//   - uint4 gathers (16B/lane): 16-lane groups own 8 features; 4 groups =
//     4 edges per wave-load; 2 gathers/iter = 8 edges. 800K -> 400K instrs.
//   - software-pipelined srcList index prefetch: next iter's indices load
//     during current iter's gathers (breaks the 2-level serial chain).
//   - tail via guarded prefetched idx regs (no scalar cleanup loop).
// Rest identical to R26 (bucketed CSR sort, 64x128 gemm, head collapse).
// ===========================================================================

__global__ __launch_bounds__(256) void bucket_hist(const int* __restrict__ col,
                                                   int* __restrict__ chunkBH,
                                                   int E, int per, int nbuck) {
    __shared__ int hist[256];
    int t = threadIdx.x;
    hist[t] = 0;
    __syncthreads();
    int s0 = blockIdx.x * per;
    int s1 = s0 + per; if (s1 > E) s1 = E;
    if (s0 < s1) {
        int q0 = s0 >> 2, q1 = s1 >> 2;
        for (int i = q0 + t; i < q1; i += 256) {
            ivec4 c = __builtin_nontemporal_load((const ivec4*)col + i);
            atomicAdd(&hist[c.x >> 8], 1);
            atomicAdd(&hist[c.y >> 8], 1);
            atomicAdd(&hist[c.z >> 8], 1);
            atomicAdd(&hist[c.w >> 8], 1);
        }
        for (int i = (q1 << 2) + t; i < s1; i += 256)
            atomicAdd(&hist[col[i] >> 8], 1);
    }
    __syncthreads();
    if (t < nbuck) chunkBH[blockIdx.x * 256 + t] = hist[t];   // [k][b], coalesced
}

__global__ __launch_bounds__(256) void bucket_scan(int* __restrict__ chunkBH,
                                                   int* __restrict__ bucketStart,
                                                   int* __restrict__ rowPtr,
                                                   int E, int n, int nbuck, int nb) {
    __shared__ int tot[256];
    int t = threadIdx.x;
    int run = 0;
    if (t < nbuck) {
        for (int k0 = 0; k0 < nb; k0 += 16) {
            int v[16];
#pragma unroll
            for (int j = 0; j < 16; j++)
                v[j] = (k0 + j < nb) ? chunkBH[(k0 + j) * 256 + t] : 0;
#pragma unroll
            for (int j = 0; j < 16; j++) {
                int tv = v[j];
                if (k0 + j < nb) chunkBH[(k0 + j) * 256 + t] = run;
                run += tv;
            }
        }
    }
    tot[t] = run;
    __syncthreads();
    for (int d = 1; d < 256; d <<= 1) {
        int add = (t >= d) ? tot[t - d] : 0;
        __syncthreads();
        tot[t] += add;
        __syncthreads();
    }
    if (t < nbuck) bucketStart[t] = tot[t] - run;
    if (t == 0) { bucketStart[nbuck] = E; rowPtr[n] = E; }
}

__global__ __launch_bounds__(256) void scatter_pairs(const int* __restrict__ row,
                                                     const int* __restrict__ col,
                                                     const int* __restrict__ chunkBH,
                                                     const int* __restrict__ bucketStart,
                                                     unsigned long long* __restrict__ tmp,
                                                     int E, int per, int nbuck) {
    __shared__ int curs[256];
    int t = threadIdx.x;
    int k = blockIdx.x;
    curs[t] = (t < nbuck) ? (chunkBH[k * 256 + t] + bucketStart[t]) : 0;
    __syncthreads();
    int s0 = k * per;
    int s1 = s0 + per; if (s1 > E) s1 = E;
    if (s0 >= s1) return;
    int q0 = s0 >> 2, q1 = s1 >> 2;
    for (int i = q0 + t; i < q1; i += 256) {
        ivec4 c4 = __builtin_nontemporal_load((const ivec4*)col + i);
        ivec4 r4 = __builtin_nontemporal_load((const ivec4*)row + i);
        int p0 = atomicAdd(&curs[c4.x >> 8], 1);
        tmp[p0] = ((unsigned long long)(unsigned)c4.x << 32) | (unsigned)r4.x;
        int p1 = atomicAdd(&curs[c4.y >> 8], 1);
        tmp[p1] = ((unsigned long long)(unsigned)c4.y << 32) | (unsigned)r4.y;
        int p2 = atomicAdd(&curs[c4.z >> 8], 1);
        tmp[p2] = ((unsigned long long)(unsigned)c4.z << 32) | (unsigned)r4.z;
        int p3 = atomicAdd(&curs[c4.w >> 8], 1);
        tmp[p3] = ((unsigned long long)(unsigned)c4.w << 32) | (unsigned)r4.w;
    }
    for (int i = (q1 << 2) + t; i < s1; i += 256) {
        int c = col[i], r = row[i];
        int p = atomicAdd(&curs[c >> 8], 1);
        tmp[p] = ((unsigned long long)(unsigned)c << 32) | (unsigned)r;
    }
}

__global__ __launch_bounds__(256) void bucket_fill(const unsigned long long* __restrict__ tmp,
                                                   const int* __restrict__ bucketStart,
                                                   int* __restrict__ rowPtr,
                                                   float* __restrict__ dinv,
                                                   int* __restrict__ srcList,
                                                   int n) {
    __shared__ int cnt[256];
    __shared__ int cur[256];
    __shared__ int seg[SEGCAP];
    int b = blockIdx.x, t = threadIdx.x;
    int node0 = b << 8;
    int s0 = bucketStart[b], s1 = bucketStart[b + 1];
    int len = s1 - s0;
    cnt[t] = 0;
    __syncthreads();
    for (int i = s0 + t; i < s1; i += 256) {
        int c = (int)(tmp[i] >> 32);
        atomicAdd(&cnt[c - node0], 1);
    }
    __syncthreads();
    int v = cnt[t];
    cur[t] = v;
    __syncthreads();
    for (int d = 1; d < 256; d <<= 1) {
        int add = (t >= d) ? cur[t - d] : 0;
        __syncthreads();
        cur[t] += add;
        __syncthreads();
    }
    int excl = cur[t] - v;
    int node = node0 + t;
    if (node < n) {
        rowPtr[node] = s0 + excl;
        dinv[node] = rsqrtf((float)v + 1.0f);   // +1 self-loop
    }
    cur[t] = excl;
    __syncthreads();
    if (len <= SEGCAP) {
        for (int i = s0 + t; i < s1; i += 256) {
            unsigned long long p = tmp[i];
            int c = (int)(p >> 32);
            int r = (int)(p & 0xffffffffu);
            int pos = atomicAdd(&cur[c - node0], 1);
            seg[pos] = r;
        }
        __syncthreads();
        for (int i = t; i < len; i += 256)
            srcList[s0 + i] = seg[i];
    } else {                                    // overflow fallback (never for this graph)
        for (int i = s0 + t; i < s1; i += 256) {
            unsigned long long p = tmp[i];
            int c = (int)(p >> 32);
            int r = (int)(p & 0xffffffffu);
            int pos = atomicAdd(&cur[c - node0], 1);
            srcList[s0 + pos] = r;
        }
    }
}

// ---------------------------------------------------------------------------
// GEMM v2: 64x128 block tile, 256 threads, 4x8 per thread, BK=16 (R25).
// ---------------------------------------------------------------------------
__global__ __launch_bounds__(256) void gemm_nk(const float* __restrict__ A,
                                               const float* __restrict__ W,
                                               const float* __restrict__ bias,
                                               const float* __restrict__ dinv,
                                               float* __restrict__ C,
                                               unsigned short* __restrict__ Cb,
                                               int n, int addb) {
    __shared__ float As[16][68];
    __shared__ float Ws[16][144];

    const int tx = threadIdx.x;
    const int row0 = blockIdx.x * 64;
    const int jg = (tx & 15) * 8;      // output col group (8 cols)
    const int ig = (tx >> 4) * 4;      // output row group (4 rows)
    const int js = jg + ((jg >> 5) << 2);   // swizzled Ws col

    const int ar  = tx >> 2;           // 0..63 : A-stage row
    const int ac4 = (tx & 3) * 4;      // 0,4,8,12 : A-stage k base
    const int growA = row0 + ar;
    const float* Ap = A + (size_t)growA * 128 + ac4;

    float acc[4][8];
#pragma unroll
    for (int r = 0; r < 4; r++)
#pragma unroll
        for (int c = 0; c < 8; c++) acc[r][c] = 0.f;

    for (int k0 = 0; k0 < 128; k0 += 16) {
        float4 va = make_float4(0.f, 0.f, 0.f, 0.f);
        if (growA < n) va = *(const float4*)(Ap + k0);
        As[ac4 + 0][ar] = va.x;
        As[ac4 + 1][ar] = va.y;
        As[ac4 + 2][ar] = va.z;
        As[ac4 + 3][ar] = va.w;
#pragma unroll
        for (int q = 0; q < 2; q++) {
            int f = tx * 2 + q;
            int kr = f >> 5;                 // 0..15
            int c4 = (f & 31) * 4;           // 0..124
            int cs = c4 + ((c4 >> 5) << 2);  // swizzle
            *(float4*)&Ws[kr][cs] = *(const float4*)(W + (size_t)(k0 + kr) * 128 + c4);
        }
        __syncthreads();
#pragma unroll
        for (int kk = 0; kk < 16; kk++) {
            float4 a4 = *(const float4*)&As[kk][ig];
            float4 w0 = *(const float4*)&Ws[kk][js];
            float4 w1 = *(const float4*)&Ws[kk][js + 4];
            float av[4] = {a4.x, a4.y, a4.z, a4.w};
            float wv[8] = {w0.x, w0.y, w0.z, w0.w, w1.x, w1.y, w1.z, w1.w};
#pragma unroll
            for (int r = 0; r < 4; r++)
#pragma unroll
                for (int c = 0; c < 8; c++) acc[r][c] += av[r] * wv[c];
        }
        __syncthreads();
    }

    float bv[8] = {0.f, 0.f, 0.f, 0.f, 0.f, 0.f, 0.f, 0.f};
    if (addb) {
        float4 b0 = *(const float4*)(bias + jg);
        float4 b1 = *(const float4*)(bias + jg + 4);
        bv[0] = b0.x; bv[1] = b0.y; bv[2] = b0.z; bv[3] = b0.w;
        bv[4] = b1.x; bv[5] = b1.y; bv[6] = b1.z; bv[7] = b1.w;
    }
#pragma unroll
    for (int r = 0; r < 4; r++) {
        int grow = row0 + ig + r;
        if (grow < n) {
            float o[8];
#pragma unroll
            for (int c = 0; c < 8; c++) o[c] = acc[r][c] + bv[c];
            *(float4*)(C + (size_t)grow * 128 + jg)     = make_float4(o[0], o[1], o[2], o[3]);
            *(float4*)(C + (size_t)grow * 128 + jg + 4) = make_float4(o[4], o[5], o[6], o[7]);
            if (Cb) {
                float dr = dinv[grow];
                ushort4 u0, u1;
                __hip_bfloat16 t;
                t = __float2bfloat16(o[0] * dr); u0.x = *(unsigned short*)&t;
                t = __float2bfloat16(o[1] * dr); u0.y = *(unsigned short*)&t;
                t = __float2bfloat16(o[2] * dr); u0.z = *(unsigned short*)&t;
                t = __float2bfloat16(o[3] * dr); u0.w = *(unsigned short*)&t;
                t = __float2bfloat16(o[4] * dr); u1.x = *(unsigned short*)&t;
                t = __float2bfloat16(o[5] * dr); u1.y = *(unsigned short*)&t;
                t = __float2bfloat16(o[6] * dr); u1.z = *(unsigned short*)&t;
                t = __float2bfloat16(o[7] * dr); u1.w = *(unsigned short*)&t;
                *(ushort4*)(Cb + (size_t)grow * 128 + jg)     = u0;
                *(ushort4*)(Cb + (size_t)grow * 128 + jg + 4) = u1;
            }
        }
    }
}

// ---------------------------------------------------------------------------
// agg_post v4: wave = 1 node. 16-lane groups: lane = 16g+h owns features
// 8h..8h+7 (uint4); groups g=0..3 take edges e+g. 2 gathers/iter = 8 edges,
// srcList indices software-pipelined one iteration ahead.
// ---------------------------------------------------------------------------
#define BF_LO(u) __uint_as_float((u) << 16)
#define BF_HI(u) __uint_as_float((u) & 0xffff0000u)

template<bool DO_LN>
__global__ __launch_bounds__(128) void agg_post(const float* __restrict__ hsrc,
                                                const unsigned int* __restrict__ hb,
                                                const int* __restrict__ rowPtr,
                                                const int* __restrict__ srcList,
                                                const float* __restrict__ dinv,
                                                const float* __restrict__ b,
                                                const float* __restrict__ g,
                                                const float* __restrict__ beta,
                                                float* __restrict__ out, int n) {
    int wid = (blockIdx.x * 128 + threadIdx.x) >> 6;
    int lane = threadIdx.x & 63;
    if (wid >= n) return;
    int h = lane & 15;          // feature octet: features 8h..8h+7
    int gg = lane >> 4;         // edge group 0..3
    int e0 = rowPtr[wid], e1 = rowPtr[wid + 1];
    float dc = dinv[wid];
    const uint4* hb4 = (const uint4*)hb;   // 16 uint4 per 128-feature row

    float a[8];
#pragma unroll
    for (int j = 0; j < 8; j++) a[j] = 0.f;

    // prologue: prefetch first two indices for this group
    int idx0 = (e0 + gg < e1) ? srcList[e0 + gg] : -1;
    int idx1 = (e0 + 4 + gg < e1) ? srcList[e0 + 4 + gg] : -1;

    int e = e0;
    for (; e + 8 <= e1; e += 8) {
        int ni0 = (e + 8 + gg < e1) ? srcList[e + 8 + gg] : -1;
        int ni1 = (e + 12 + gg < e1) ? srcList[e + 12 + gg] : -1;
        uint4 u0 = hb4[(size_t)idx0 * 16 + h];
        uint4 u1 = hb4[(size_t)idx1 * 16 + h];
        a[0] += BF_LO(u0.x); a[1] += BF_HI(u0.x);
        a[2] += BF_LO(u0.y); a[3] += BF_HI(u0.y);
        a[4] += BF_LO(u0.z); a[5] += BF_HI(u0.z);
        a[6] += BF_LO(u0.w); a[7] += BF_HI(u0.w);
        a[0] += BF_LO(u1.x); a[1] += BF_HI(u1.x);
        a[2] += BF_LO(u1.y); a[3] += BF_HI(u1.y);
        a[4] += BF_LO(u1.z); a[5] += BF_HI(u1.z);
        a[6] += BF_LO(u1.w); a[7] += BF_HI(u1.w);
        idx0 = ni0; idx1 = ni1;
    }
    // tail (< 8 edges): idx0 covers e+gg, idx1 covers e+4+gg, both guarded
    if (idx0 >= 0) {
        uint4 u = hb4[(size_t)idx0 * 16 + h];
        a[0] += BF_LO(u.x); a[1] += BF_HI(u.x);
        a[2] += BF_LO(u.y); a[3] += BF_HI(u.y);
        a[4] += BF_LO(u.z); a[5] += BF_HI(u.z);
        a[6] += BF_LO(u.w); a[7] += BF_HI(u.w);
    }
    if (idx1 >= 0) {
        uint4 u = hb4[(size_t)idx1 * 16 + h];
        a[0] += BF_LO(u.x); a[1] += BF_HI(u.x);
        a[2] += BF_LO(u.y); a[3] += BF_HI(u.y);
        a[4] += BF_LO(u.z); a[5] += BF_HI(u.z);
        a[6] += BF_LO(u.w); a[7] += BF_HI(u.w);
    }

    // merge the 4 edge-groups (feature octet identical across groups)
#pragma unroll
    for (int j = 0; j < 8; j++) {
        a[j] += __shfl_xor(a[j], 16, 64);
        a[j] += __shfl_xor(a[j], 32, 64);
    }

    // scale + self-loop(f32) + bias + relu
    float4 hs0 = *(const float4*)(hsrc + (size_t)wid * 128 + h * 8);
    float4 hs1 = *(const float4*)(hsrc + (size_t)wid * 128 + h * 8 + 4);
    float4 bv0 = *(const float4*)(b + h * 8);
    float4 bv1 = *(const float4*)(b + h * 8 + 4);
    float dc2 = dc * dc;
    a[0] = fmaxf(a[0] * dc + hs0.x * dc2 + bv0.x, 0.f);
    a[1] = fmaxf(a[1] * dc + hs0.y * dc2 + bv0.y, 0.f);
    a[2] = fmaxf(a[2] * dc + hs0.z * dc2 + bv0.z, 0.f);
    a[3] = fmaxf(a[3] * dc + hs0.w * dc2 + bv0.w, 0.f);
    a[4] = fmaxf(a[4] * dc + hs1.x * dc2 + bv1.x, 0.f);
    a[5] = fmaxf(a[5] * dc + hs1.y * dc2 + bv1.y, 0.f);
    a[6] = fmaxf(a[6] * dc + hs1.z * dc2 + bv1.z, 0.f);
    a[7] = fmaxf(a[7] * dc + hs1.w * dc2 + bv1.w, 0.f);

    if (DO_LN) {
        float s = ((a[0] + a[1]) + (a[2] + a[3])) + ((a[4] + a[5]) + (a[6] + a[7]));
#pragma unroll
        for (int m = 8; m >= 1; m >>= 1) s += __shfl_xor(s, m, 64);
        float mu = s * (1.f / 128.f);
        float sq = 0.f;
        float d[8];
#pragma unroll
        for (int j = 0; j < 8; j++) { d[j] = a[j] - mu; sq += d[j] * d[j]; }
#pragma unroll
        for (int m = 8; m >= 1; m >>= 1) sq += __shfl_xor(sq, m, 64);
        float rs = rsqrtf(sq * (1.f / 128.f) + EPS_LN);
        float4 gv0 = *(const float4*)(g + h * 8);
        float4 gv1 = *(const float4*)(g + h * 8 + 4);
        float4 bt0 = *(const float4*)(beta + h * 8);
        float4 bt1 = *(const float4*)(beta + h * 8 + 4);
        a[0] = d[0] * rs * gv0.x + bt0.x;
        a[1] = d[1] * rs * gv0.y + bt0.y;
        a[2] = d[2] * rs * gv0.z + bt0.z;
        a[3] = d[3] * rs * gv0.w + bt0.w;
        a[4] = d[4] * rs * gv1.x + bt1.x;
        a[5] = d[5] * rs * gv1.y + bt1.y;
        a[6] = d[6] * rs * gv1.z + bt1.z;
        a[7] = d[7] * rs * gv1.w + bt1.w;
    }
    if (gg == 0) {
        *(float4*)(out + (size_t)wid * 128 + h * 8)     = make_float4(a[0], a[1], a[2], a[3]);
        *(float4*)(out + (size_t)wid * 128 + h * 8 + 4) = make_float4(a[4], a[5], a[6], a[7]);
    }
}

// ---------------------------------------------------------------------------
// Head collapse: Weff = Wp1 @ Wp2 (128x3), beff = bp1 @ Wp2 + bp2.
// ---------------------------------------------------------------------------
__global__ __launch_bounds__(128) void head_collapse(const float* __restrict__ Wp1,
                                                     const float* __restrict__ bp1,
                                                     const float* __restrict__ Wp2,
                                                     const float* __restrict__ bp2,
                                                     float* __restrict__ Weff,
                                                     float* __restrict__ beff) {
    __shared__ float w2[384];
    int t = threadIdx.x;
    w2[t] = Wp2[t]; w2[t + 128] = Wp2[t + 128]; w2[t + 256] = Wp2[t + 256];
    __syncthreads();
    float p0 = 0.f, p1 = 0.f, p2 = 0.f;
    const float* wr = Wp1 + (size_t)t * 128;
    for (int k = 0; k < 128; k++) {
        float v = wr[k];
        p0 += v * w2[k * 3 + 0];
        p1 += v * w2[k * 3 + 1];
        p2 += v * w2[k * 3 + 2];
    }
    Weff[t * 3 + 0] = p0; Weff[t * 3 + 1] = p1; Weff[t * 3 + 2] = p2;
    if (t == 0) {
        float q0 = bp2[0], q1 = bp2[1], q2 = bp2[2];
        for (int k = 0; k < 128; k++) {
            float v = bp1[k];
            q0 += v * w2[k * 3 + 0];
            q1 += v * w2[k * 3 + 1];
            q2 += v * w2[k * 3 + 2];
        }
        beff[0] = q0; beff[1] = q1; beff[2] = q2;
    }
}

// ---------------------------------------------------------------------------
__global__ __launch_bounds__(256) void nhead_f32(const float* __restrict__ hp,
                                                 const float* __restrict__ W,
                                                 const float* __restrict__ b,
                                                 float* __restrict__ out, int n) {
    __shared__ float Ws[384];
    int t = threadIdx.x;
    if (t < 192) { Ws[t] = W[t]; Ws[t + 192] = W[t + 192]; }
    __syncthreads();
    int i = blockIdx.x * 256 + t;
    if (i >= n) return;
    float p0 = b[0], p1 = b[1], p2 = b[2];
    const float4* h4 = (const float4*)(hp + (size_t)i * 128);
#pragma unroll
    for (int k4 = 0; k4 < 32; k4++) {
        float4 v = h4[k4];
        const float* w = &Ws[k4 * 12];
        p0 += v.x * w[0] + v.y * w[3] + v.z * w[6] + v.w * w[9];
        p1 += v.x * w[1] + v.y * w[4] + v.z * w[7] + v.w * w[10];
        p2 += v.x * w[2] + v.y * w[5] + v.z * w[8] + v.w * w[11];
    }
    out[(size_t)i * 3 + 0] = p0;
    out[(size_t)i * 3 + 1] = p1;
    out[(size_t)i * 3 + 2] = p2;
}

// ---------------------------------------------------------------------------
extern "C" void kernel_launch(void* const* d_in, const int* in_sizes, int n_in,
                              void* d_out, int out_size, void* d_ws, size_t ws_size,
                              hipStream_t stream) {
    const float* x   = (const float*)d_in[0];
    const int* ei    = (const int*)d_in[1];
    const float* W1  = (const float*)d_in[2];
    const float* b1  = (const float*)d_in[3];
    const float* W2  = (const float*)d_in[4];
    const float* b2  = (const float*)d_in[5];
    const float* W3  = (const float*)d_in[6];
    const float* b3  = (const float*)d_in[7];
    const float* g1  = (const float*)d_in[8];
    const float* be1 = (const float*)d_in[9];
    const float* g2  = (const float*)d_in[10];
    const float* be2 = (const float*)d_in[11];
    const float* Wp1 = (const float*)d_in[12];
    const float* bp1 = (const float*)d_in[13];
    const float* Wp2 = (const float*)d_in[14];
    const float* bp2 = (const float*)d_in[15];
    float* out = (float*)d_out;

    const int n = in_sizes[0] / 128;   // 50000
    const int E = in_sizes[1] / 2;     // 1600000
    const int* row = ei;
    const int* col = ei + E;

    char* ws = (char*)d_ws;
    size_t nA  = ((size_t)n * 4 + 255) & ~(size_t)255;
    size_t nA1 = ((size_t)(n + 1) * 4 + 255) & ~(size_t)255;
    size_t eA  = ((size_t)E * 4 + 255) & ~(size_t)255;
    size_t hbA = ((size_t)n * 128 * 2 + 255) & ~(size_t)255;
    int*   rowPtr  = (int*)ws;
    float* dinvp   = (float*)(ws + nA1);
    int*   srcList = (int*)(ws + nA1 + nA);
    unsigned short* hb = (unsigned short*)(ws + nA1 + nA + eA);
    float* bufA    = (float*)(ws + nA1 + nA + eA + hbA);
    float* bufB    = bufA + (size_t)n * 128;
    float* Weff    = bufB + (size_t)n * 128;     // 384 floats
    float* beff    = Weff + 384;                 // 3 floats
    // CSR scratch aliases bufA (25.6MB; consumed before layer-1 gemm):
    unsigned long long* tmp = (unsigned long long*)bufA;
    int* chunkBH    = (int*)((char*)bufA + 2 * eA);
    int* bucketStart = (int*)((char*)bufA + 2 * eA + (size_t)NB * 256 * 4);

    const int nbuck = (n + 255) >> 8;                 // 196
    const int per   = (((E + NB - 1) / NB) + 15) & ~15;  // 16-aligned chunk size
    const int gemmBlocks = (n + 63) / 64;             // 782
    const int nodeWaveBlocks = (n + 1) / 2;           // 2 waves/block
    const int nodeBlocks = (n + 255) / 256;

    // CSR build (bucketed counting sort, zero global atomics)
    bucket_hist<<<NB, 256, 0, stream>>>(col, chunkBH, E, per, nbuck);
    bucket_scan<<<1, 256, 0, stream>>>(chunkBH, bucketStart, rowPtr, E, n, nbuck, NB);
    scatter_pairs<<<NB, 256, 0, stream>>>(row, col, chunkBH, bucketStart, tmp, E, per, nbuck);
    bucket_fill<<<nbuck, 256, 0, stream>>>(tmp, bucketStart, rowPtr, dinvp, srcList, n);
    head_collapse<<<1, 128, 0, stream>>>(Wp1, bp1, Wp2, bp2, Weff, beff);

    // ---- layer 1 ----
    gemm_nk<<<gemmBlocks, 256, 0, stream>>>(x, W1, b1, dinvp, bufA, hb, n, 0);
    agg_post<true><<<nodeWaveBlocks, 128, 0, stream>>>(bufA, (const unsigned int*)hb,
                                                       rowPtr, srcList, dinvp,
                                                       b1, g1, be1, bufB, n);
    // ---- layer 2 ----
    gemm_nk<<<gemmBlocks, 256, 0, stream>>>(bufB, W2, b2, dinvp, bufA, hb, n, 0);
    agg_post<true><<<nodeWaveBlocks, 128, 0, stream>>>(bufA, (const unsigned int*)hb,
                                                       rowPtr, srcList, dinvp,
                                                       b2, g2, be2, bufB, n);
    // ---- layer 3 (relu, no LN) ----
    gemm_nk<<<gemmBlocks, 256, 0, stream>>>(bufB, W3, b3, dinvp, bufA, hb, n, 0);
    agg_post<false><<<nodeWaveBlocks, 128, 0, stream>>>(bufA, (const unsigned int*)hb,
                                                        rowPtr, srcList, dinvp,
                                                        b3, b3, b3, bufB, n);
    // ---- collapsed MLP head ----
    nhead_f32<<<nodeBlocks, 256, 0, stream>>>(bufB, Weff, beff, out, n);
}

// Round 8
// 415.671 us; speedup vs baseline: 1.3707x; 1.0192x over previous
//
#include <hip/hip_runtime.h>
#include <hip/hip_bf16.h>

#define EPS_LN 1e-5f
#define NB    256             // edge chunks for hist/scatter
#define SEGCAP 16384          // srcList segment capacity per bucket (64KB LDS)

typedef int ivec4 __attribute__((ext_vector_type(4)));

// ===========================================================================
// R28: delete redundant streams. R27 post-mortem: agg_post FETCH (166MB) is at
// the compulsory floor (8 XCD x 12.8MB hb + 25.6MB h-self + srcList); it is
// HBM-bound on traffic, not instructions. hb = C*dinv already contains the
// self-loop signal: self = C*dc^2 = hb[wid]*dc (one extra bf16 rounding on 1
// of ~33 terms). So:
//   - gemm_hb writes ONLY the bf16 hb (C f32 write deleted: -25.6MB/layer)
//   - agg_post reads self from hb[wid] (f32 h read deleted: -25.6MB/layer)
// Rest identical to R27 (bucketed CSR sort, uint4 pipelined gather, head
// collapse).
// ===========================================================================

__global__ __launch_bounds__(256) void bucket_hist(const int* __restrict__ col,
                                                   int* __restrict__ chunkBH,
                                                   int E, int per, int nbuck) {
    __shared__ int hist[256];
    int t = threadIdx.x;
    hist[t] = 0;
    __syncthreads();
    int s0 = blockIdx.x * per;
    int s1 = s0 + per; if (s1 > E) s1 = E;
    if (s0 < s1) {
        int q0 = s0 >> 2, q1 = s1 >> 2;
        for (int i = q0 + t; i < q1; i += 256) {
            ivec4 c = __builtin_nontemporal_load((const ivec4*)col + i);
            atomicAdd(&hist[c.x >> 8], 1);
            atomicAdd(&hist[c.y >> 8], 1);
            atomicAdd(&hist[c.z >> 8], 1);
            atomicAdd(&hist[c.w >> 8], 1);
        }
        for (int i = (q1 << 2) + t; i < s1; i += 256)
            atomicAdd(&hist[col[i] >> 8], 1);
    }
    __syncthreads();
    if (t < nbuck) chunkBH[blockIdx.x * 256 + t] = hist[t];   // [k][b], coalesced
}

__global__ __launch_bounds__(256) void bucket_scan(int* __restrict__ chunkBH,
                                                   int* __restrict__ bucketStart,
                                                   int* __restrict__ rowPtr,
                                                   int E, int n, int nbuck, int nb) {
    __shared__ int tot[256];
    int t = threadIdx.x;
    int run = 0;
    if (t < nbuck) {
        for (int k0 = 0; k0 < nb; k0 += 16) {
            int v[16];
#pragma unroll
            for (int j = 0; j < 16; j++)
                v[j] = (k0 + j < nb) ? chunkBH[(k0 + j) * 256 + t] : 0;
#pragma unroll
            for (int j = 0; j < 16; j++) {
                int tv = v[j];
                if (k0 + j < nb) chunkBH[(k0 + j) * 256 + t] = run;
                run += tv;
            }
        }
    }
    tot[t] = run;
    __syncthreads();
    for (int d = 1; d < 256; d <<= 1) {
        int add = (t >= d) ? tot[t - d] : 0;
        __syncthreads();
        tot[t] += add;
        __syncthreads();
    }
    if (t < nbuck) bucketStart[t] = tot[t] - run;
    if (t == 0) { bucketStart[nbuck] = E; rowPtr[n] = E; }
}

__global__ __launch_bounds__(256) void scatter_pairs(const int* __restrict__ row,
                                                     const int* __restrict__ col,
                                                     const int* __restrict__ chunkBH,
                                                     const int* __restrict__ bucketStart,
                                                     unsigned long long* __restrict__ tmp,
                                                     int E, int per, int nbuck) {
    __shared__ int curs[256];
    int t = threadIdx.x;
    int k = blockIdx.x;
    curs[t] = (t < nbuck) ? (chunkBH[k * 256 + t] + bucketStart[t]) : 0;
    __syncthreads();
    int s0 = k * per;
    int s1 = s0 + per; if (s1 > E) s1 = E;
    if (s0 >= s1) return;
    int q0 = s0 >> 2, q1 = s1 >> 2;
    for (int i = q0 + t; i < q1; i += 256) {
        ivec4 c4 = __builtin_nontemporal_load((const ivec4*)col + i);
        ivec4 r4 = __builtin_nontemporal_load((const ivec4*)row + i);
        int p0 = atomicAdd(&curs[c4.x >> 8], 1);
        tmp[p0] = ((unsigned long long)(unsigned)c4.x << 32) | (unsigned)r4.x;
        int p1 = atomicAdd(&curs[c4.y >> 8], 1);
        tmp[p1] = ((unsigned long long)(unsigned)c4.y << 32) | (unsigned)r4.y;
        int p2 = atomicAdd(&curs[c4.z >> 8], 1);
        tmp[p2] = ((unsigned long long)(unsigned)c4.z << 32) | (unsigned)r4.z;
        int p3 = atomicAdd(&curs[c4.w >> 8], 1);
        tmp[p3] = ((unsigned long long)(unsigned)c4.w << 32) | (unsigned)r4.w;
    }
    for (int i = (q1 << 2) + t; i < s1; i += 256) {
        int c = col[i], r = row[i];
        int p = atomicAdd(&curs[c >> 8], 1);
        tmp[p] = ((unsigned long long)(unsigned)c << 32) | (unsigned)r;
    }
}

__global__ __launch_bounds__(256) void bucket_fill(const unsigned long long* __restrict__ tmp,
                                                   const int* __restrict__ bucketStart,
                                                   int* __restrict__ rowPtr,
                                                   float* __restrict__ dinv,
                                                   int* __restrict__ srcList,
                                                   int n) {
    __shared__ int cnt[256];
    __shared__ int cur[256];
    __shared__ int seg[SEGCAP];
    int b = blockIdx.x, t = threadIdx.x;
    int node0 = b << 8;
    int s0 = bucketStart[b], s1 = bucketStart[b + 1];
    int len = s1 - s0;
    cnt[t] = 0;
    __syncthreads();
    for (int i = s0 + t; i < s1; i += 256) {
        int c = (int)(tmp[i] >> 32);
        atomicAdd(&cnt[c - node0], 1);
    }
    __syncthreads();
    int v = cnt[t];
    cur[t] = v;
    __syncthreads();
    for (int d = 1; d < 256; d <<= 1) {
        int add = (t >= d) ? cur[t - d] : 0;
        __syncthreads();
        cur[t] += add;
        __syncthreads();
    }
    int excl = cur[t] - v;
    int node = node0 + t;
    if (node < n) {
        rowPtr[node] = s0 + excl;
        dinv[node] = rsqrtf((float)v + 1.0f);   // +1 self-loop
    }
    cur[t] = excl;
    __syncthreads();
    if (len <= SEGCAP) {
        for (int i = s0 + t; i < s1; i += 256) {
            unsigned long long p = tmp[i];
            int c = (int)(p >> 32);
            int r = (int)(p & 0xffffffffu);
            int pos = atomicAdd(&cur[c - node0], 1);
            seg[pos] = r;
        }
        __syncthreads();
        for (int i = t; i < len; i += 256)
            srcList[s0 + i] = seg[i];
    } else {                                    // overflow fallback (never for this graph)
        for (int i = s0 + t; i < s1; i += 256) {
            unsigned long long p = tmp[i];
            int c = (int)(p >> 32);
            int r = (int)(p & 0xffffffffu);
            int pos = atomicAdd(&cur[c - node0], 1);
            srcList[s0 + pos] = r;
        }
    }
}

// ---------------------------------------------------------------------------
// GEMM v3: 64x128 tile, 256 threads, 4x8/thread, BK=16. Emits ONLY the
// pre-scaled bf16 hb = (A@W)*dinv — the f32 C write is deleted (R28).
// ---------------------------------------------------------------------------
__global__ __launch_bounds__(256) void gemm_hb(const float* __restrict__ A,
                                               const float* __restrict__ W,
                                               const float* __restrict__ dinv,
                                               unsigned short* __restrict__ Cb,
                                               int n) {
    __shared__ float As[16][68];
    __shared__ float Ws[16][144];

    const int tx = threadIdx.x;
    const int row0 = blockIdx.x * 64;
    const int jg = (tx & 15) * 8;      // output col group (8 cols)
    const int ig = (tx >> 4) * 4;      // output row group (4 rows)
    const int js = jg + ((jg >> 5) << 2);   // swizzled Ws col

    const int ar  = tx >> 2;           // 0..63 : A-stage row
    const int ac4 = (tx & 3) * 4;      // 0,4,8,12 : A-stage k base
    const int growA = row0 + ar;
    const float* Ap = A + (size_t)growA * 128 + ac4;

    float acc[4][8];
#pragma unroll
    for (int r = 0; r < 4; r++)
#pragma unroll
        for (int c = 0; c < 8; c++) acc[r][c] = 0.f;

    for (int k0 = 0; k0 < 128; k0 += 16) {
        float4 va = make_float4(0.f, 0.f, 0.f, 0.f);
        if (growA < n) va = *(const float4*)(Ap + k0);
        As[ac4 + 0][ar] = va.x;
        As[ac4 + 1][ar] = va.y;
        As[ac4 + 2][ar] = va.z;
        As[ac4 + 3][ar] = va.w;
#pragma unroll
        for (int q = 0; q < 2; q++) {
            int f = tx * 2 + q;
            int kr = f >> 5;                 // 0..15
            int c4 = (f & 31) * 4;           // 0..124
            int cs = c4 + ((c4 >> 5) << 2);  // swizzle
            *(float4*)&Ws[kr][cs] = *(const float4*)(W + (size_t)(k0 + kr) * 128 + c4);
        }
        __syncthreads();
#pragma unroll
        for (int kk = 0; kk < 16; kk++) {
            float4 a4 = *(const float4*)&As[kk][ig];
            float4 w0 = *(const float4*)&Ws[kk][js];
            float4 w1 = *(const float4*)&Ws[kk][js + 4];
            float av[4] = {a4.x, a4.y, a4.z, a4.w};
            float wv[8] = {w0.x, w0.y, w0.z, w0.w, w1.x, w1.y, w1.z, w1.w};
#pragma unroll
            for (int r = 0; r < 4; r++)
#pragma unroll
                for (int c = 0; c < 8; c++) acc[r][c] += av[r] * wv[c];
        }
        __syncthreads();
    }

#pragma unroll
    for (int r = 0; r < 4; r++) {
        int grow = row0 + ig + r;
        if (grow < n) {
            float dr = dinv[grow];
            ushort4 u0, u1;
            __hip_bfloat16 t;
            t = __float2bfloat16(acc[r][0] * dr); u0.x = *(unsigned short*)&t;
            t = __float2bfloat16(acc[r][1] * dr); u0.y = *(unsigned short*)&t;
            t = __float2bfloat16(acc[r][2] * dr); u0.z = *(unsigned short*)&t;
            t = __float2bfloat16(acc[r][3] * dr); u0.w = *(unsigned short*)&t;
            t = __float2bfloat16(acc[r][4] * dr); u1.x = *(unsigned short*)&t;
            t = __float2bfloat16(acc[r][5] * dr); u1.y = *(unsigned short*)&t;
            t = __float2bfloat16(acc[r][6] * dr); u1.z = *(unsigned short*)&t;
            t = __float2bfloat16(acc[r][7] * dr); u1.w = *(unsigned short*)&t;
            *(ushort4*)(Cb + (size_t)grow * 128 + jg)     = u0;
            *(ushort4*)(Cb + (size_t)grow * 128 + jg + 4) = u1;
        }
    }
}

// ---------------------------------------------------------------------------
// agg_post v5: wave = 1 node; 16-lane groups own feature octets (uint4);
// groups g=0..3 take edges e+g; srcList indices pipelined. Self-loop comes
// from hb[wid] (R28): self = hb*dc, same scaling as gather terms.
// ---------------------------------------------------------------------------
#define BF_LO(u) __uint_as_float((u) << 16)
#define BF_HI(u) __uint_as_float((u) & 0xffff0000u)

template<bool DO_LN>
__global__ __launch_bounds__(128) void agg_post(const unsigned int* __restrict__ hb,
                                                const int* __restrict__ rowPtr,
                                                const int* __restrict__ srcList,
                                                const float* __restrict__ dinv,
                                                const float* __restrict__ b,
                                                const float* __restrict__ g,
                                                const float* __restrict__ beta,
                                                float* __restrict__ out, int n) {
    int wid = (blockIdx.x * 128 + threadIdx.x) >> 6;
    int lane = threadIdx.x & 63;
    if (wid >= n) return;
    int h = lane & 15;          // feature octet: features 8h..8h+7
    int gg = lane >> 4;         // edge group 0..3
    int e0 = rowPtr[wid], e1 = rowPtr[wid + 1];
    float dc = dinv[wid];
    const uint4* hb4 = (const uint4*)hb;   // 16 uint4 per 128-feature row

    // self row (issued early; consumed after the merge)
    uint4 us = hb4[(size_t)wid * 16 + h];

    float a[8];
#pragma unroll
    for (int j = 0; j < 8; j++) a[j] = 0.f;

    // prologue: prefetch first two indices for this group
    int idx0 = (e0 + gg < e1) ? srcList[e0 + gg] : -1;
    int idx1 = (e0 + 4 + gg < e1) ? srcList[e0 + 4 + gg] : -1;

    int e = e0;
    for (; e + 8 <= e1; e += 8) {
        int ni0 = (e + 8 + gg < e1) ? srcList[e + 8 + gg] : -1;
        int ni1 = (e + 12 + gg < e1) ? srcList[e + 12 + gg] : -1;
        uint4 u0 = hb4[(size_t)idx0 * 16 + h];
        uint4 u1 = hb4[(size_t)idx1 * 16 + h];
        a[0] += BF_LO(u0.x); a[1] += BF_HI(u0.x);
        a[2] += BF_LO(u0.y); a[3] += BF_HI(u0.y);
        a[4] += BF_LO(u0.z); a[5] += BF_HI(u0.z);
        a[6] += BF_LO(u0.w); a[7] += BF_HI(u0.w);
        a[0] += BF_LO(u1.x); a[1] += BF_HI(u1.x);
        a[2] += BF_LO(u1.y); a[3] += BF_HI(u1.y);
        a[4] += BF_LO(u1.z); a[5] += BF_HI(u1.z);
        a[6] += BF_LO(u1.w); a[7] += BF_HI(u1.w);
        idx0 = ni0; idx1 = ni1;
    }
    // tail (< 8 edges): idx0 covers e+gg, idx1 covers e+4+gg, both guarded
    if (idx0 >= 0) {
        uint4 u = hb4[(size_t)idx0 * 16 + h];
        a[0] += BF_LO(u.x); a[1] += BF_HI(u.x);
        a[2] += BF_LO(u.y); a[3] += BF_HI(u.y);
        a[4] += BF_LO(u.z); a[5] += BF_HI(u.z);
        a[6] += BF_LO(u.w); a[7] += BF_HI(u.w);
    }
    if (idx1 >= 0) {
        uint4 u = hb4[(size_t)idx1 * 16 + h];
        a[0] += BF_LO(u.x); a[1] += BF_HI(u.x);
        a[2] += BF_LO(u.y); a[3] += BF_HI(u.y);
        a[4] += BF_LO(u.z); a[5] += BF_HI(u.z);
        a[6] += BF_LO(u.w); a[7] += BF_HI(u.w);
    }

    // merge the 4 edge-groups (feature octet identical across groups)
#pragma unroll
    for (int j = 0; j < 8; j++) {
        a[j] += __shfl_xor(a[j], 16, 64);
        a[j] += __shfl_xor(a[j], 32, 64);
    }

    // self-loop (same dc scaling as gather terms), bias, relu
    a[0] += BF_LO(us.x); a[1] += BF_HI(us.x);
    a[2] += BF_LO(us.y); a[3] += BF_HI(us.y);
    a[4] += BF_LO(us.z); a[5] += BF_HI(us.z);
    a[6] += BF_LO(us.w); a[7] += BF_HI(us.w);

    float4 bv0 = *(const float4*)(b + h * 8);
    float4 bv1 = *(const float4*)(b + h * 8 + 4);
    a[0] = fmaxf(a[0] * dc + bv0.x, 0.f);
    a[1] = fmaxf(a[1] * dc + bv0.y, 0.f);
    a[2] = fmaxf(a[2] * dc + bv0.z, 0.f);
    a[3] = fmaxf(a[3] * dc + bv0.w, 0.f);
    a[4] = fmaxf(a[4] * dc + bv1.x, 0.f);
    a[5] = fmaxf(a[5] * dc + bv1.y, 0.f);
    a[6] = fmaxf(a[6] * dc + bv1.z, 0.f);
    a[7] = fmaxf(a[7] * dc + bv1.w, 0.f);

    if (DO_LN) {
        float s = ((a[0] + a[1]) + (a[2] + a[3])) + ((a[4] + a[5]) + (a[6] + a[7]));
#pragma unroll
        for (int m = 8; m >= 1; m >>= 1) s += __shfl_xor(s, m, 64);
        float mu = s * (1.f / 128.f);
        float sq = 0.f;
        float d[8];
#pragma unroll
        for (int j = 0; j < 8; j++) { d[j] = a[j] - mu; sq += d[j] * d[j]; }
#pragma unroll
        for (int m = 8; m >= 1; m >>= 1) sq += __shfl_xor(sq, m, 64);
        float rs = rsqrtf(sq * (1.f / 128.f) + EPS_LN);
        float4 gv0 = *(const float4*)(g + h * 8);
        float4 gv1 = *(const float4*)(g + h * 8 + 4);
        float4 bt0 = *(const float4*)(beta + h * 8);
        float4 bt1 = *(const float4*)(beta + h * 8 + 4);
        a[0] = d[0] * rs * gv0.x + bt0.x;
        a[1] = d[1] * rs * gv0.y + bt0.y;
        a[2] = d[2] * rs * gv0.z + bt0.z;
        a[3] = d[3] * rs * gv0.w + bt0.w;
        a[4] = d[4] * rs * gv1.x + bt1.x;
        a[5] = d[5] * rs * gv1.y + bt1.y;
        a[6] = d[6] * rs * gv1.z + bt1.z;
        a[7] = d[7] * rs * gv1.w + bt1.w;
    }
    if (gg == 0) {
        *(float4*)(out + (size_t)wid * 128 + h * 8)     = make_float4(a[0], a[1], a[2], a[3]);
        *(float4*)(out + (size_t)wid * 128 + h * 8 + 4) = make_float4(a[4], a[5], a[6], a[7]);
    }
}

// ---------------------------------------------------------------------------
// Head collapse: Weff = Wp1 @ Wp2 (128x3), beff = bp1 @ Wp2 + bp2.
// ---------------------------------------------------------------------------
__global__ __launch_bounds__(128) void head_collapse(const float* __restrict__ Wp1,
                                                     const float* __restrict__ bp1,
                                                     const float* __restrict__ Wp2,
                                                     const float* __restrict__ bp2,
                                                     float* __restrict__ Weff,
                                                     float* __restrict__ beff) {
    __shared__ float w2[384];
    int t = threadIdx.x;
    w2[t] = Wp2[t]; w2[t + 128] = Wp2[t + 128]; w2[t + 256] = Wp2[t + 256];
    __syncthreads();
    float p0 = 0.f, p1 = 0.f, p2 = 0.f;
    const float* wr = Wp1 + (size_t)t * 128;
    for (int k = 0; k < 128; k++) {
        float v = wr[k];
        p0 += v * w2[k * 3 + 0];
        p1 += v * w2[k * 3 + 1];
        p2 += v * w2[k * 3 + 2];
    }
    Weff[t * 3 + 0] = p0; Weff[t * 3 + 1] = p1; Weff[t * 3 + 2] = p2;
    if (t == 0) {
        float q0 = bp2[0], q1 = bp2[1], q2 = bp2[2];
        for (int k = 0; k < 128; k++) {
            float v = bp1[k];
            q0 += v * w2[k * 3 + 0];
            q1 += v * w2[k * 3 + 1];
            q2 += v * w2[k * 3 + 2];
        }
        beff[0] = q0; beff[1] = q1; beff[2] = q2;
    }
}

// ---------------------------------------------------------------------------
__global__ __launch_bounds__(256) void nhead_f32(const float* __restrict__ hp,
                                                 const float* __restrict__ W,
                                                 const float* __restrict__ b,
                                                 float* __restrict__ out, int n) {
    __shared__ float Ws[384];
    int t = threadIdx.x;
    if (t < 192) { Ws[t] = W[t]; Ws[t + 192] = W[t + 192]; }
    __syncthreads();
    int i = blockIdx.x * 256 + t;
    if (i >= n) return;
    float p0 = b[0], p1 = b[1], p2 = b[2];
    const float4* h4 = (const float4*)(hp + (size_t)i * 128);
#pragma unroll
    for (int k4 = 0; k4 < 32; k4++) {
        float4 v = h4[k4];
        const float* w = &Ws[k4 * 12];
        p0 += v.x * w[0] + v.y * w[3] + v.z * w[6] + v.w * w[9];
        p1 += v.x * w[1] + v.y * w[4] + v.z * w[7] + v.w * w[10];
        p2 += v.x * w[2] + v.y * w[5] + v.z * w[8] + v.w * w[11];
    }
    out[(size_t)i * 3 + 0] = p0;
    out[(size_t)i * 3 + 1] = p1;
    out[(size_t)i * 3 + 2] = p2;
}

// ---------------------------------------------------------------------------
extern "C" void kernel_launch(void* const* d_in, const int* in_sizes, int n_in,
                              void* d_out, int out_size, void* d_ws, size_t ws_size,
                              hipStream_t stream) {
    const float* x   = (const float*)d_in[0];
    const int* ei    = (const int*)d_in[1];
    const float* W1  = (const float*)d_in[2];
    const float* b1  = (const float*)d_in[3];
    const float* W2  = (const float*)d_in[4];
    const float* b2  = (const float*)d_in[5];
    const float* W3  = (const float*)d_in[6];
    const float* b3  = (const float*)d_in[7];
    const float* g1  = (const float*)d_in[8];
    const float* be1 = (const float*)d_in[9];
    const float* g2  = (const float*)d_in[10];
    const float* be2 = (const float*)d_in[11];
    const float* Wp1 = (const float*)d_in[12];
    const float* bp1 = (const float*)d_in[13];
    const float* Wp2 = (const float*)d_in[14];
    const float* bp2 = (const float*)d_in[15];
    float* out = (float*)d_out;

    const int n = in_sizes[0] / 128;   // 50000
    const int E = in_sizes[1] / 2;     // 1600000
    const int* row = ei;
    const int* col = ei + E;

    char* ws = (char*)d_ws;
    size_t nA  = ((size_t)n * 4 + 255) & ~(size_t)255;
    size_t nA1 = ((size_t)(n + 1) * 4 + 255) & ~(size_t)255;
    size_t eA  = ((size_t)E * 4 + 255) & ~(size_t)255;
    size_t hbA = ((size_t)n * 128 * 2 + 255) & ~(size_t)255;
    int*   rowPtr  = (int*)ws;
    float* dinvp   = (float*)(ws + nA1);
    int*   srcList = (int*)(ws + nA1 + nA);
    unsigned short* hb = (unsigned short*)(ws + nA1 + nA + eA);
    float* bufA    = (float*)(ws + nA1 + nA + eA + hbA);
    float* bufB    = bufA + (size_t)n * 128;
    float* Weff    = bufB + (size_t)n * 128;     // 384 floats
    float* beff    = Weff + 384;                 // 3 floats
    // CSR scratch aliases bufA (25.6MB; consumed before layer-2 agg writes):
    unsigned long long* tmp = (unsigned long long*)bufA;
    int* chunkBH    = (int*)((char*)bufA + 2 * eA);
    int* bucketStart = (int*)((char*)bufA + 2 * eA + (size_t)NB * 256 * 4);

    const int nbuck = (n + 255) >> 8;                 // 196
    const int per   = (((E + NB - 1) / NB) + 15) & ~15;  // 16-aligned chunk size
    const int gemmBlocks = (n + 63) / 64;             // 782
    const int nodeWaveBlocks = (n + 1) / 2;           // 2 waves/block
    const int nodeBlocks = (n + 255) / 256;

    // CSR build (bucketed counting sort, zero global atomics)
    bucket_hist<<<NB, 256, 0, stream>>>(col, chunkBH, E, per, nbuck);
    bucket_scan<<<1, 256, 0, stream>>>(chunkBH, bucketStart, rowPtr, E, n, nbuck, NB);
    scatter_pairs<<<NB, 256, 0, stream>>>(row, col, chunkBH, bucketStart, tmp, E, per, nbuck);
    bucket_fill<<<nbuck, 256, 0, stream>>>(tmp, bucketStart, rowPtr, dinvp, srcList, n);
    head_collapse<<<1, 128, 0, stream>>>(Wp1, bp1, Wp2, bp2, Weff, beff);

    // ---- layer 1 ----
    gemm_hb<<<gemmBlocks, 256, 0, stream>>>(x, W1, dinvp, hb, n);
    agg_post<true><<<nodeWaveBlocks, 128, 0, stream>>>((const unsigned int*)hb,
                                                       rowPtr, srcList, dinvp,
                                                       b1, g1, be1, bufB, n);
    // ---- layer 2 ----
    gemm_hb<<<gemmBlocks, 256, 0, stream>>>(bufB, W2, dinvp, hb, n);
    agg_post<true><<<nodeWaveBlocks, 128, 0, stream>>>((const unsigned int*)hb,
                                                       rowPtr, srcList, dinvp,
                                                       b2, g2, be2, bufA, n);
    // ---- layer 3 (relu, no LN) ----
    gemm_hb<<<gemmBlocks, 256, 0, stream>>>(bufA, W3, dinvp, hb, n);
    agg_post<false><<<nodeWaveBlocks, 128, 0, stream>>>((const unsigned int*)hb,
                                                        rowPtr, srcList, dinvp,
                                                        b3, b3, b3, bufB, n);
    // ---- collapsed MLP head ----
    nhead_f32<<<nodeBlocks, 256, 0, stream>>>(bufB, Weff, beff, out, n);
}